// Round 1
// baseline (2282.602 us; speedup 1.0000x reference)
//
#include <hip/hip_runtime.h>

#define NN 100000

// ---- detect whether edge_index is int64 (hi words all zero) or int32 ----
__global__ __launch_bounds__(64) void k_detect(const unsigned int* ei, int* flag) {
    if (threadIdx.x == 0) {
        int is64 = 1;
        for (int i = 0; i < 64; ++i)
            if (ei[2 * i + 1] != 0u) { is64 = 0; break; }
        *flag = is64;
    }
}

__global__ __launch_bounds__(256) void k_deg(const int* __restrict__ ei32,
                                             const long long* __restrict__ ei64,
                                             const int* __restrict__ flag,
                                             int E, float* __restrict__ deg) {
    int e = blockIdx.x * 256 + threadIdx.x;
    if (e >= E) return;
    int dst = (*flag) ? (int)ei64[(long long)E + e] : ei32[E + e];
    atomicAdd(&deg[dst], 1.0f);
}

__global__ __launch_bounds__(256) void k_dinv(float* deg, int n) {
    int i = blockIdx.x * 256 + threadIdx.x;
    if (i < n) deg[i] = rsqrtf(deg[i] + 1.0f);
}

// ---- skinny GEMM: H[N,C] = X[N,K] @ W[K,C] ----
template <int K, int C, int RPT>
__global__ __launch_bounds__(256) void k_gemm(const float* __restrict__ X,
                                              const float* __restrict__ W,
                                              float* __restrict__ H, int n) {
    constexpr int CG = C / 4;        // col groups (4 cols each)
    constexpr int RS = 256 / CG;     // row slots
    constexpr int RT = RS * RPT;     // rows per tile
    constexpr int XS = K + 4;        // padded LDS stride (bank spread, float4-aligned)
    __shared__ float Ws[K * C];
    __shared__ float Xs[RT * XS];
    const int t = threadIdx.x;

    for (int i = t * 4; i < K * C; i += 1024)
        *(float4*)&Ws[i] = *(const float4*)&W[i];

    const int row0 = blockIdx.x * RT;
    for (int i = t * 4; i < RT * K; i += 1024) {
        int r = i / K, k = i % K;
        int gr = row0 + r;
        float4 v = make_float4(0.f, 0.f, 0.f, 0.f);
        if (gr < n) v = *(const float4*)&X[(long long)gr * K + k];
        *(float4*)&Xs[r * XS + k] = v;
    }
    __syncthreads();

    const int cg = t % CG, rs = t / CG;
    float acc[RPT][4];
#pragma unroll
    for (int i = 0; i < RPT; ++i)
#pragma unroll
        for (int j = 0; j < 4; ++j) acc[i][j] = 0.f;

#pragma unroll 4
    for (int k = 0; k < K; ++k) {
        float4 w = *(float4*)&Ws[k * C + cg * 4];
#pragma unroll
        for (int i = 0; i < RPT; ++i) {
            float xv = Xs[(rs * RPT + i) * XS + k];
            acc[i][0] = fmaf(xv, w.x, acc[i][0]);
            acc[i][1] = fmaf(xv, w.y, acc[i][1]);
            acc[i][2] = fmaf(xv, w.z, acc[i][2]);
            acc[i][3] = fmaf(xv, w.w, acc[i][3]);
        }
    }
#pragma unroll
    for (int i = 0; i < RPT; ++i) {
        int gr = row0 + rs * RPT + i;
        if (gr < n)
            *(float4*)&H[(long long)gr * C + cg * 4] =
                make_float4(acc[i][0], acc[i][1], acc[i][2], acc[i][3]);
    }
}

// ---- edge scatter: agg[dst] += h[src] * dinv[src]*dinv[dst]  (wave per edge) ----
template <int F>
__global__ __launch_bounds__(256) void k_scatter(const float* __restrict__ h,
                                                 const int* __restrict__ ei32,
                                                 const long long* __restrict__ ei64,
                                                 const int* __restrict__ flag,
                                                 const float* __restrict__ dinv,
                                                 float* __restrict__ agg, int E) {
    int wave = blockIdx.x * 4 + (threadIdx.x >> 6);
    int lane = threadIdx.x & 63;
    if (wave >= E) return;
    int src, dst;
    if (*flag) {
        src = (int)ei64[wave];
        dst = (int)ei64[(long long)E + wave];
    } else {
        src = ei32[wave];
        dst = ei32[E + wave];
    }
    float norm = dinv[src] * dinv[dst];
    const float* hr = h + (long long)src * F;
    float* ar = agg + (long long)dst * F;
#pragma unroll
    for (int f = lane; f < F; f += 64)
        atomicAdd(&ar[f], hr[f] * norm);
}

// ---- h = relu(agg + h*dinv^2 + b)  (in-place on h, float4 per thread) ----
template <int F>
__global__ __launch_bounds__(256) void k_self(const float* __restrict__ agg,
                                              float* __restrict__ h,
                                              const float* __restrict__ dinv,
                                              const float* __restrict__ bias, int n) {
    constexpr int FQ = F / 4;
    int i4 = blockIdx.x * 256 + threadIdx.x;
    int node = i4 / FQ;
    if (node >= n) return;
    int fq = i4 % FQ;
    float d = dinv[node];
    float d2 = d * d;
    long long base = (long long)node * F + fq * 4;
    float4 hv = *(const float4*)&h[base];
    float4 av = *(const float4*)&agg[base];
    float4 bv = *(const float4*)&bias[fq * 4];
    float4 r;
    r.x = fmaxf(fmaf(hv.x, d2, av.x) + bv.x, 0.f);
    r.y = fmaxf(fmaf(hv.y, d2, av.y) + bv.y, 0.f);
    r.z = fmaxf(fmaf(hv.z, d2, av.z) + bv.z, 0.f);
    r.w = fmaxf(fmaf(hv.w, d2, av.w) + bv.w, 0.f);
    *(float4*)&h[base] = r;
}

// ---- fused: out[n] = sum_f relu(agg2 + h2*dinv^2 + b2)[f] * Wfc[f] + bfc ----
__global__ __launch_bounds__(256) void k_final(const float* __restrict__ h2,
                                               const float* __restrict__ agg2,
                                               const float* __restrict__ dinv,
                                               const float* __restrict__ b2,
                                               const float* __restrict__ Wfc,
                                               const float* __restrict__ bfc,
                                               float* __restrict__ out, int n) {
    int node = blockIdx.x * 4 + (threadIdx.x >> 6);
    int lane = threadIdx.x & 63;
    if (node >= n) return;
    float d = dinv[node];
    float d2 = d * d;
    const float* hr = h2 + (long long)node * 128;
    const float* ar = agg2 + (long long)node * 128;
    float acc = 0.f;
#pragma unroll
    for (int j = 0; j < 2; ++j) {
        int f = lane + j * 64;
        float v = fmaxf(fmaf(hr[f], d2, ar[f]) + b2[f], 0.f);
        acc = fmaf(v, Wfc[f], acc);
    }
#pragma unroll
    for (int off = 32; off; off >>= 1) acc += __shfl_down(acc, off, 64);
    if (lane == 0) out[node] = acc + bfc[0];
}

extern "C" void kernel_launch(void* const* d_in, const int* in_sizes, int n_in,
                              void* d_out, int out_size, void* d_ws, size_t ws_size,
                              hipStream_t stream) {
    const float* x   = (const float*)d_in[0];
    const void*  ei  = d_in[1];
    const float* W1  = (const float*)d_in[2];
    const float* b1  = (const float*)d_in[3];
    const float* W2  = (const float*)d_in[4];
    const float* b2  = (const float*)d_in[5];
    const float* Wfc = (const float*)d_in[6];
    const float* bfc = (const float*)d_in[7];
    float* out = (float*)d_out;

    const int N = NN;
    const int E = in_sizes[1] / 2;

    char* ws = (char*)d_ws;
    float* dinv = (float*)ws;                                  // N floats
    int*   flag = (int*)(ws + (size_t)N * 4);
    size_t offA = (((size_t)N * 4 + 4) + 255) & ~(size_t)255;
    float* bufA = (float*)(ws + offA);                         // N*128 floats
    float* bufB = (float*)(ws + offA + (size_t)N * 128 * 4);   // N*128 floats

    const int* ei32 = (const int*)ei;
    const long long* ei64 = (const long long*)ei;

    // degree + rsqrt
    hipMemsetAsync(dinv, 0, (size_t)N * 4, stream);
    k_detect<<<1, 64, 0, stream>>>((const unsigned int*)ei, flag);
    k_deg<<<(E + 255) / 256, 256, 0, stream>>>(ei32, ei64, flag, E, dinv);
    k_dinv<<<(N + 255) / 256, 256, 0, stream>>>(dinv, N);

    // layer 1: h1 = x @ W1  -> bufA[:, :64]
    k_gemm<128, 64, 2><<<(N + 31) / 32, 256, 0, stream>>>(x, W1, bufA, N);
    hipMemsetAsync(bufB, 0, (size_t)N * 64 * 4, stream);
    k_scatter<64><<<(E + 3) / 4, 256, 0, stream>>>(bufA, ei32, ei64, flag, dinv, bufB, E);
    k_self<64><<<(N * 16 + 255) / 256, 256, 0, stream>>>(bufB, bufA, dinv, b1, N);

    // layer 2: h2 = h1out @ W2 -> bufB[N,128]
    k_gemm<64, 128, 4><<<(N + 31) / 32, 256, 0, stream>>>(bufA, W2, bufB, N);
    hipMemsetAsync(bufA, 0, (size_t)N * 128 * 4, stream);
    k_scatter<128><<<(E + 3) / 4, 256, 0, stream>>>(bufB, ei32, ei64, flag, dinv, bufA, E);

    // fused epilogue + FC
    k_final<<<(N + 3) / 4, 256, 0, stream>>>(bufB, bufA, dinv, b2, Wfc, bfc, out, N);
}

// Round 2
// 986.636 us; speedup vs baseline: 2.3135x; 2.3135x over previous
//
#include <hip/hip_runtime.h>

#define NN 100000

// ---- detect whether edge_index is int64 (hi words all zero) or int32 ----
__global__ __launch_bounds__(64) void k_detect(const unsigned int* ei, int* flag) {
    if (threadIdx.x == 0) {
        int is64 = 1;
        for (int i = 0; i < 64; ++i)
            if (ei[2 * i + 1] != 0u) { is64 = 0; break; }
        *flag = is64;
    }
}

__global__ __launch_bounds__(256) void k_hist(const int* __restrict__ ei32,
                                              const long long* __restrict__ ei64,
                                              const int* __restrict__ flag,
                                              int E, int* __restrict__ degi) {
    int e = blockIdx.x * 256 + threadIdx.x;
    if (e >= E) return;
    int dst = (*flag) ? (int)ei64[(long long)E + e] : ei32[E + e];
    atomicAdd(&degi[dst], 1);
}

__global__ __launch_bounds__(256) void k_dinv(const int* __restrict__ degi,
                                              float* __restrict__ dinv, int n) {
    int i = blockIdx.x * 256 + threadIdx.x;
    if (i < n) dinv[i] = rsqrtf((float)degi[i] + 1.0f);
}

// ---- 3-step exclusive scan of degi -> row_ptr (and cursor copy) ----
__global__ __launch_bounds__(256) void k_scan1(const int* __restrict__ degi,
                                               int* __restrict__ bsum, int n) {
    __shared__ int s[256];
    int t = threadIdx.x;
    int i = blockIdx.x * 256 + t;
    s[t] = (i < n) ? degi[i] : 0;
    __syncthreads();
    for (int off = 128; off; off >>= 1) {
        if (t < off) s[t] += s[t + off];
        __syncthreads();
    }
    if (t == 0) bsum[blockIdx.x] = s[0];
}

__global__ __launch_bounds__(64) void k_scan2(int* __restrict__ bsum, int nb,
                                              int* __restrict__ row_ptr, int n, int E) {
    if (threadIdx.x == 0) {
        int run = 0;
        for (int b = 0; b < nb; ++b) {
            int v = bsum[b];
            bsum[b] = run;
            run += v;
        }
        row_ptr[n] = E;
    }
}

__global__ __launch_bounds__(256) void k_scan3(const int* __restrict__ degi,
                                               const int* __restrict__ bsum,
                                               int* __restrict__ row_ptr,
                                               int* __restrict__ cursor, int n) {
    __shared__ int s[256];
    int t = threadIdx.x;
    int i = blockIdx.x * 256 + t;
    int v = (i < n) ? degi[i] : 0;
    s[t] = v;
    __syncthreads();
    for (int off = 1; off < 256; off <<= 1) {
        int add = (t >= off) ? s[t - off] : 0;
        __syncthreads();
        s[t] += add;
        __syncthreads();
    }
    int row = bsum[blockIdx.x] + s[t] - v;  // exclusive
    if (i < n) {
        row_ptr[i] = row;
        cursor[i] = row;
    }
}

__global__ __launch_bounds__(256) void k_fill(const int* __restrict__ ei32,
                                              const long long* __restrict__ ei64,
                                              const int* __restrict__ flag,
                                              int E, int* __restrict__ cursor,
                                              int* __restrict__ csr) {
    int e = blockIdx.x * 256 + threadIdx.x;
    if (e >= E) return;
    int src, dst;
    if (*flag) {
        src = (int)ei64[e];
        dst = (int)ei64[(long long)E + e];
    } else {
        src = ei32[e];
        dst = ei32[E + e];
    }
    int slot = atomicAdd(&cursor[dst], 1);
    csr[slot] = src;
}

// ---- skinny GEMM: H[N,C] = X[N,K] @ W[K,C] ----
template <int K, int C, int RPT>
__global__ __launch_bounds__(256) void k_gemm(const float* __restrict__ X,
                                              const float* __restrict__ W,
                                              float* __restrict__ H, int n) {
    constexpr int CG = C / 4;
    constexpr int RS = 256 / CG;
    constexpr int RT = RS * RPT;
    constexpr int XS = K + 4;
    __shared__ float Ws[K * C];
    __shared__ float Xs[RT * XS];
    const int t = threadIdx.x;

    for (int i = t * 4; i < K * C; i += 1024)
        *(float4*)&Ws[i] = *(const float4*)&W[i];

    const int row0 = blockIdx.x * RT;
    for (int i = t * 4; i < RT * K; i += 1024) {
        int r = i / K, k = i % K;
        int gr = row0 + r;
        float4 v = make_float4(0.f, 0.f, 0.f, 0.f);
        if (gr < n) v = *(const float4*)&X[(long long)gr * K + k];
        *(float4*)&Xs[r * XS + k] = v;
    }
    __syncthreads();

    const int cg = t % CG, rs = t / CG;
    float acc[RPT][4];
#pragma unroll
    for (int i = 0; i < RPT; ++i)
#pragma unroll
        for (int j = 0; j < 4; ++j) acc[i][j] = 0.f;

#pragma unroll 4
    for (int k = 0; k < K; ++k) {
        float4 w = *(float4*)&Ws[k * C + cg * 4];
#pragma unroll
        for (int i = 0; i < RPT; ++i) {
            float xv = Xs[(rs * RPT + i) * XS + k];
            acc[i][0] = fmaf(xv, w.x, acc[i][0]);
            acc[i][1] = fmaf(xv, w.y, acc[i][1]);
            acc[i][2] = fmaf(xv, w.z, acc[i][2]);
            acc[i][3] = fmaf(xv, w.w, acc[i][3]);
        }
    }
#pragma unroll
    for (int i = 0; i < RPT; ++i) {
        int gr = row0 + rs * RPT + i;
        if (gr < n)
            *(float4*)&H[(long long)gr * C + cg * 4] =
                make_float4(acc[i][0], acc[i][1], acc[i][2], acc[i][3]);
    }
}

// ---- gather layer 1 (F=64): out = relu(sum_in + self + b), wave per node ----
__global__ __launch_bounds__(256) void k_gather1(const float* __restrict__ h,
                                                 const int* __restrict__ row_ptr,
                                                 const int* __restrict__ csr,
                                                 const float* __restrict__ dinv,
                                                 const float* __restrict__ bias,
                                                 float* __restrict__ out, int n) {
    int node = blockIdx.x * 4 + (threadIdx.x >> 6);
    int lane = threadIdx.x & 63;
    if (node >= n) return;
    float d = dinv[node];
    int beg = row_ptr[node], end = row_ptr[node + 1];
    float acc = 0.f;
    int i = beg;
    for (; i + 1 < end; i += 2) {
        int s0 = csr[i], s1 = csr[i + 1];
        float n0 = dinv[s0] * d, n1 = dinv[s1] * d;
        float x0 = h[(long long)s0 * 64 + lane];
        float x1 = h[(long long)s1 * 64 + lane];
        acc = fmaf(x0, n0, acc);
        acc = fmaf(x1, n1, acc);
    }
    if (i < end) {
        int s0 = csr[i];
        acc = fmaf(h[(long long)s0 * 64 + lane], dinv[s0] * d, acc);
    }
    float self = h[(long long)node * 64 + lane];
    float v = fmaxf(fmaf(self, d * d, acc) + bias[lane], 0.f);
    out[(long long)node * 64 + lane] = v;
}

// ---- gather layer 2 (F=128) + fused FC: out[node] = relu(...)·Wfc + bfc ----
__global__ __launch_bounds__(256) void k_gather2(const float* __restrict__ h,
                                                 const int* __restrict__ row_ptr,
                                                 const int* __restrict__ csr,
                                                 const float* __restrict__ dinv,
                                                 const float* __restrict__ b2,
                                                 const float* __restrict__ Wfc,
                                                 const float* __restrict__ bfc,
                                                 float* __restrict__ out, int n) {
    int node = blockIdx.x * 4 + (threadIdx.x >> 6);
    int lane = threadIdx.x & 63;
    if (node >= n) return;
    float d = dinv[node];
    int beg = row_ptr[node], end = row_ptr[node + 1];
    float acc0 = 0.f, acc1 = 0.f;
    int i = beg;
    for (; i + 1 < end; i += 2) {
        int s0 = csr[i], s1 = csr[i + 1];
        float n0 = dinv[s0] * d, n1 = dinv[s1] * d;
        const float* r0 = h + (long long)s0 * 128;
        const float* r1 = h + (long long)s1 * 128;
        float a0 = r0[lane], a1 = r0[lane + 64];
        float c0 = r1[lane], c1 = r1[lane + 64];
        acc0 = fmaf(a0, n0, acc0);
        acc1 = fmaf(a1, n0, acc1);
        acc0 = fmaf(c0, n1, acc0);
        acc1 = fmaf(c1, n1, acc1);
    }
    if (i < end) {
        int s0 = csr[i];
        float n0 = dinv[s0] * d;
        const float* r0 = h + (long long)s0 * 128;
        acc0 = fmaf(r0[lane], n0, acc0);
        acc1 = fmaf(r0[lane + 64], n0, acc1);
    }
    float d2 = d * d;
    const float* hs = h + (long long)node * 128;
    float v0 = fmaxf(fmaf(hs[lane], d2, acc0) + b2[lane], 0.f);
    float v1 = fmaxf(fmaf(hs[lane + 64], d2, acc1) + b2[lane + 64], 0.f);
    float acc = fmaf(v0, Wfc[lane], v1 * Wfc[lane + 64]);
#pragma unroll
    for (int off = 32; off; off >>= 1) acc += __shfl_down(acc, off, 64);
    if (lane == 0) out[node] = acc + bfc[0];
}

extern "C" void kernel_launch(void* const* d_in, const int* in_sizes, int n_in,
                              void* d_out, int out_size, void* d_ws, size_t ws_size,
                              hipStream_t stream) {
    const float* x   = (const float*)d_in[0];
    const void*  ei  = d_in[1];
    const float* W1  = (const float*)d_in[2];
    const float* b1  = (const float*)d_in[3];
    const float* W2  = (const float*)d_in[4];
    const float* b2  = (const float*)d_in[5];
    const float* Wfc = (const float*)d_in[6];
    const float* bfc = (const float*)d_in[7];
    float* out = (float*)d_out;

    const int N = NN;
    const int E = in_sizes[1] / 2;
    const int NB = (N + 255) / 256;

    // workspace carve-up (256B aligned)
    char* ws = (char*)d_ws;
    size_t o = 0;
    auto carve = [&](size_t bytes) {
        char* p = ws + o;
        o = (o + bytes + 255) & ~(size_t)255;
        return p;
    };
    int*   degi    = (int*)carve((size_t)N * 4);
    float* dinv    = (float*)carve((size_t)N * 4);
    int*   row_ptr = (int*)carve((size_t)(N + 1) * 4);
    int*   cursor  = (int*)carve((size_t)N * 4);
    int*   bsum    = (int*)carve((size_t)NB * 4);
    int*   flag    = (int*)carve(4);
    int*   csr     = (int*)carve((size_t)E * 4);
    float* bufA    = (float*)carve((size_t)N * 128 * 4);
    float* bufB    = (float*)carve((size_t)N * 64 * 4);

    const int* ei32 = (const int*)ei;
    const long long* ei64 = (const long long*)ei;

    // ---- degree + dinv + CSR build (reused by both layers) ----
    hipMemsetAsync(degi, 0, (size_t)N * 4, stream);
    k_detect<<<1, 64, 0, stream>>>((const unsigned int*)ei, flag);
    k_hist<<<(E + 255) / 256, 256, 0, stream>>>(ei32, ei64, flag, E, degi);
    k_dinv<<<(N + 255) / 256, 256, 0, stream>>>(degi, dinv, N);
    k_scan1<<<NB, 256, 0, stream>>>(degi, bsum, N);
    k_scan2<<<1, 64, 0, stream>>>(bsum, NB, row_ptr, N, E);
    k_scan3<<<NB, 256, 0, stream>>>(degi, bsum, row_ptr, cursor, N);
    k_fill<<<(E + 255) / 256, 256, 0, stream>>>(ei32, ei64, flag, E, cursor, csr);

    // ---- layer 1: h1 = x @ W1 (bufA as N x 64); gather+self+bias+relu -> bufB ----
    k_gemm<128, 64, 2><<<(N + 31) / 32, 256, 0, stream>>>(x, W1, bufA, N);
    k_gather1<<<(N + 3) / 4, 256, 0, stream>>>(bufA, row_ptr, csr, dinv, b1, bufB, N);

    // ---- layer 2: h2 = h1r @ W2 (bufA as N x 128); gather+epilogue+FC -> out ----
    k_gemm<64, 128, 4><<<(N + 31) / 32, 256, 0, stream>>>(bufB, W2, bufA, N);
    k_gather2<<<(N + 3) / 4, 256, 0, stream>>>(bufA, row_ptr, csr, dinv, b2, Wfc, bfc, out, N);
}

// Round 3
// 689.545 us; speedup vs baseline: 3.3103x; 1.4309x over previous
//
#include <hip/hip_runtime.h>

#define NN 100000
#define NRANGE 8
#define RANGE_SZ (NN / NRANGE)   // 12500 exactly

// ---- detect whether edge_index is int64 (hi words all zero) or int32 ----
__global__ __launch_bounds__(64) void k_detect(const unsigned int* ei, int* flag) {
    if (threadIdx.x == 0) {
        int is64 = 1;
        for (int i = 0; i < 64; ++i)
            if (ei[2 * i + 1] != 0u) { is64 = 0; break; }
        *flag = is64;
    }
}

__global__ __launch_bounds__(256) void k_hist(const int* __restrict__ ei32,
                                              const long long* __restrict__ ei64,
                                              const int* __restrict__ flag,
                                              int E, int* __restrict__ degi) {
    int e = blockIdx.x * 256 + threadIdx.x;
    if (e >= E) return;
    int dst = (*flag) ? (int)ei64[(long long)E + e] : ei32[E + e];
    atomicAdd(&degi[dst], 1);
}

__global__ __launch_bounds__(256) void k_dinv(const int* __restrict__ degi,
                                              float* __restrict__ dinv, int n) {
    int i = blockIdx.x * 256 + threadIdx.x;
    if (i < n) dinv[i] = rsqrtf((float)degi[i] + 1.0f);
}

// ---- 3-step exclusive scan of degi -> row_ptr (and cursor copy) ----
__global__ __launch_bounds__(256) void k_scan1(const int* __restrict__ degi,
                                               int* __restrict__ bsum, int n) {
    __shared__ int s[256];
    int t = threadIdx.x;
    int i = blockIdx.x * 256 + t;
    s[t] = (i < n) ? degi[i] : 0;
    __syncthreads();
    for (int off = 128; off; off >>= 1) {
        if (t < off) s[t] += s[t + off];
        __syncthreads();
    }
    if (t == 0) bsum[blockIdx.x] = s[0];
}

// single-block parallel exclusive scan of block sums (nb <= 512)
__global__ __launch_bounds__(512) void k_scan2(int* __restrict__ bsum, int nb,
                                               int* __restrict__ row_ptr, int n, int E) {
    __shared__ int s[512];
    int t = threadIdx.x;
    int v = (t < nb) ? bsum[t] : 0;
    s[t] = v;
    __syncthreads();
    for (int off = 1; off < 512; off <<= 1) {
        int add = (t >= off) ? s[t - off] : 0;
        __syncthreads();
        s[t] += add;
        __syncthreads();
    }
    if (t < nb) bsum[t] = s[t] - v;  // exclusive
    if (t == 0) row_ptr[n] = E;
}

__global__ __launch_bounds__(256) void k_scan3(const int* __restrict__ degi,
                                               const int* __restrict__ bsum,
                                               int* __restrict__ row_ptr,
                                               int* __restrict__ cursor, int n) {
    __shared__ int s[256];
    int t = threadIdx.x;
    int i = blockIdx.x * 256 + t;
    int v = (i < n) ? degi[i] : 0;
    s[t] = v;
    __syncthreads();
    for (int off = 1; off < 256; off <<= 1) {
        int add = (t >= off) ? s[t - off] : 0;
        __syncthreads();
        s[t] += add;
        __syncthreads();
    }
    int row = bsum[blockIdx.x] + s[t] - v;  // exclusive
    if (i < n) {
        row_ptr[i] = row;
        cursor[i] = row;
    }
}

// ---- CSR fill, dst-range partitioned so csr-store locality is per-XCD ----
// block b: chunk = b>>3 of the edge list, range = b&7 of dst space.
__global__ __launch_bounds__(256) void k_fill(const int* __restrict__ ei32,
                                              const long long* __restrict__ ei64,
                                              const int* __restrict__ flag,
                                              int E, int nchunks,
                                              int* __restrict__ cursor,
                                              int* __restrict__ csr) {
    int r = blockIdx.x & (NRANGE - 1);
    int chunk = blockIdx.x >> 3;
    int per = (E + nchunks - 1) / nchunks;
    int beg = chunk * per;
    int end = min(beg + per, E);
    int lo = r * RANGE_SZ, hi = lo + RANGE_SZ;
    bool is64 = (*flag) != 0;
    for (int e = beg + (int)threadIdx.x; e < end; e += 256) {
        int dst = is64 ? (int)ei64[(long long)E + e] : ei32[E + e];
        if (dst >= lo && dst < hi) {
            int src = is64 ? (int)ei64[e] : ei32[e];
            int slot = atomicAdd(&cursor[dst], 1);
            csr[slot] = src;
        }
    }
}

// ---- skinny GEMM: H[N,C] = X[N,K] @ W[K,C] ----
template <int K, int C, int RPT>
__global__ __launch_bounds__(256) void k_gemm(const float* __restrict__ X,
                                              const float* __restrict__ W,
                                              float* __restrict__ H, int n) {
    constexpr int CG = C / 4;
    constexpr int RS = 256 / CG;
    constexpr int RT = RS * RPT;
    constexpr int XS = K + 4;
    __shared__ float Ws[K * C];
    __shared__ float Xs[RT * XS];
    const int t = threadIdx.x;

    for (int i = t * 4; i < K * C; i += 1024)
        *(float4*)&Ws[i] = *(const float4*)&W[i];

    const int row0 = blockIdx.x * RT;
    for (int i = t * 4; i < RT * K; i += 1024) {
        int r = i / K, k = i % K;
        int gr = row0 + r;
        float4 v = make_float4(0.f, 0.f, 0.f, 0.f);
        if (gr < n) v = *(const float4*)&X[(long long)gr * K + k];
        *(float4*)&Xs[r * XS + k] = v;
    }
    __syncthreads();

    const int cg = t % CG, rs = t / CG;
    float acc[RPT][4];
#pragma unroll
    for (int i = 0; i < RPT; ++i)
#pragma unroll
        for (int j = 0; j < 4; ++j) acc[i][j] = 0.f;

#pragma unroll 4
    for (int k = 0; k < K; ++k) {
        float4 w = *(float4*)&Ws[k * C + cg * 4];
#pragma unroll
        for (int i = 0; i < RPT; ++i) {
            float xv = Xs[(rs * RPT + i) * XS + k];
            acc[i][0] = fmaf(xv, w.x, acc[i][0]);
            acc[i][1] = fmaf(xv, w.y, acc[i][1]);
            acc[i][2] = fmaf(xv, w.z, acc[i][2]);
            acc[i][3] = fmaf(xv, w.w, acc[i][3]);
        }
    }
#pragma unroll
    for (int i = 0; i < RPT; ++i) {
        int gr = row0 + rs * RPT + i;
        if (gr < n)
            *(float4*)&H[(long long)gr * C + cg * 4] =
                make_float4(acc[i][0], acc[i][1], acc[i][2], acc[i][3]);
    }
}

// ---- gather layer 1 (F=64): out = relu(sum_in + self + b), wave per node ----
__global__ __launch_bounds__(256) void k_gather1(const float* __restrict__ h,
                                                 const int* __restrict__ row_ptr,
                                                 const int* __restrict__ csr,
                                                 const float* __restrict__ dinv,
                                                 const float* __restrict__ bias,
                                                 float* __restrict__ out, int n) {
    int node = blockIdx.x * 4 + (threadIdx.x >> 6);
    int lane = threadIdx.x & 63;
    if (node >= n) return;
    float d = dinv[node];
    int beg = row_ptr[node], end = row_ptr[node + 1];
    float acc = 0.f;
    int i = beg;
    for (; i + 3 < end; i += 4) {
        int s0 = csr[i], s1 = csr[i + 1], s2 = csr[i + 2], s3 = csr[i + 3];
        float n0 = dinv[s0] * d, n1 = dinv[s1] * d;
        float n2 = dinv[s2] * d, n3 = dinv[s3] * d;
        float x0 = h[(long long)s0 * 64 + lane];
        float x1 = h[(long long)s1 * 64 + lane];
        float x2 = h[(long long)s2 * 64 + lane];
        float x3 = h[(long long)s3 * 64 + lane];
        acc = fmaf(x0, n0, acc);
        acc = fmaf(x1, n1, acc);
        acc = fmaf(x2, n2, acc);
        acc = fmaf(x3, n3, acc);
    }
    for (; i < end; ++i) {
        int s0 = csr[i];
        acc = fmaf(h[(long long)s0 * 64 + lane], dinv[s0] * d, acc);
    }
    float self = h[(long long)node * 64 + lane];
    float v = fmaxf(fmaf(self, d * d, acc) + bias[lane], 0.f);
    out[(long long)node * 64 + lane] = v;
}

// ---- gather layer 2 (F=128) + fused FC: out[node] = relu(...)·Wfc + bfc ----
__global__ __launch_bounds__(256) void k_gather2(const float* __restrict__ h,
                                                 const int* __restrict__ row_ptr,
                                                 const int* __restrict__ csr,
                                                 const float* __restrict__ dinv,
                                                 const float* __restrict__ b2,
                                                 const float* __restrict__ Wfc,
                                                 const float* __restrict__ bfc,
                                                 float* __restrict__ out, int n) {
    int node = blockIdx.x * 4 + (threadIdx.x >> 6);
    int lane = threadIdx.x & 63;
    if (node >= n) return;
    float d = dinv[node];
    int beg = row_ptr[node], end = row_ptr[node + 1];
    float acc0 = 0.f, acc1 = 0.f;
    int i = beg;
    for (; i + 3 < end; i += 4) {
        int s0 = csr[i], s1 = csr[i + 1], s2 = csr[i + 2], s3 = csr[i + 3];
        float n0 = dinv[s0] * d, n1 = dinv[s1] * d;
        float n2 = dinv[s2] * d, n3 = dinv[s3] * d;
        const float* r0 = h + (long long)s0 * 128;
        const float* r1 = h + (long long)s1 * 128;
        const float* r2 = h + (long long)s2 * 128;
        const float* r3 = h + (long long)s3 * 128;
        acc0 = fmaf(r0[lane], n0, acc0);
        acc1 = fmaf(r0[lane + 64], n0, acc1);
        acc0 = fmaf(r1[lane], n1, acc0);
        acc1 = fmaf(r1[lane + 64], n1, acc1);
        acc0 = fmaf(r2[lane], n2, acc0);
        acc1 = fmaf(r2[lane + 64], n2, acc1);
        acc0 = fmaf(r3[lane], n3, acc0);
        acc1 = fmaf(r3[lane + 64], n3, acc1);
    }
    for (; i < end; ++i) {
        int s0 = csr[i];
        float n0 = dinv[s0] * d;
        const float* r0 = h + (long long)s0 * 128;
        acc0 = fmaf(r0[lane], n0, acc0);
        acc1 = fmaf(r0[lane + 64], n0, acc1);
    }
    float d2 = d * d;
    const float* hs = h + (long long)node * 128;
    float v0 = fmaxf(fmaf(hs[lane], d2, acc0) + b2[lane], 0.f);
    float v1 = fmaxf(fmaf(hs[lane + 64], d2, acc1) + b2[lane + 64], 0.f);
    float acc = fmaf(v0, Wfc[lane], v1 * Wfc[lane + 64]);
#pragma unroll
    for (int off = 32; off; off >>= 1) acc += __shfl_down(acc, off, 64);
    if (lane == 0) out[node] = acc + bfc[0];
}

extern "C" void kernel_launch(void* const* d_in, const int* in_sizes, int n_in,
                              void* d_out, int out_size, void* d_ws, size_t ws_size,
                              hipStream_t stream) {
    const float* x   = (const float*)d_in[0];
    const void*  ei  = d_in[1];
    const float* W1  = (const float*)d_in[2];
    const float* b1  = (const float*)d_in[3];
    const float* W2  = (const float*)d_in[4];
    const float* b2  = (const float*)d_in[5];
    const float* Wfc = (const float*)d_in[6];
    const float* bfc = (const float*)d_in[7];
    float* out = (float*)d_out;

    const int N = NN;
    const int E = in_sizes[1] / 2;
    const int NB = (N + 255) / 256;

    // workspace carve-up (256B aligned)
    char* ws = (char*)d_ws;
    size_t o = 0;
    auto carve = [&](size_t bytes) {
        char* p = ws + o;
        o = (o + bytes + 255) & ~(size_t)255;
        return p;
    };
    int*   degi    = (int*)carve((size_t)N * 4);
    float* dinv    = (float*)carve((size_t)N * 4);
    int*   row_ptr = (int*)carve((size_t)(N + 1) * 4);
    int*   cursor  = (int*)carve((size_t)N * 4);
    int*   bsum    = (int*)carve((size_t)NB * 4);
    int*   flag    = (int*)carve(4);
    int*   csr     = (int*)carve((size_t)E * 4);
    float* bufA    = (float*)carve((size_t)N * 128 * 4);
    float* bufB    = (float*)carve((size_t)N * 64 * 4);

    const int* ei32 = (const int*)ei;
    const long long* ei64 = (const long long*)ei;

    // ---- degree + dinv + CSR build (reused by both layers) ----
    hipMemsetAsync(degi, 0, (size_t)N * 4, stream);
    k_detect<<<1, 64, 0, stream>>>((const unsigned int*)ei, flag);
    k_hist<<<(E + 255) / 256, 256, 0, stream>>>(ei32, ei64, flag, E, degi);
    k_dinv<<<(N + 255) / 256, 256, 0, stream>>>(degi, dinv, N);
    k_scan1<<<NB, 256, 0, stream>>>(degi, bsum, N);
    k_scan2<<<1, 512, 0, stream>>>(bsum, NB, row_ptr, N, E);
    k_scan3<<<NB, 256, 0, stream>>>(degi, bsum, row_ptr, cursor, N);
    const int NCHUNK = 256;
    k_fill<<<NCHUNK * NRANGE, 256, 0, stream>>>(ei32, ei64, flag, E, NCHUNK, cursor, csr);

    // ---- layer 1: h1 = x @ W1 (bufA as N x 64); gather+self+bias+relu -> bufB ----
    k_gemm<128, 64, 2><<<(N + 31) / 32, 256, 0, stream>>>(x, W1, bufA, N);
    k_gather1<<<(N + 3) / 4, 256, 0, stream>>>(bufA, row_ptr, csr, dinv, b1, bufB, N);

    // ---- layer 2: h2 = h1r @ W2 (bufA as N x 128); gather+epilogue+FC -> out ----
    k_gemm<64, 128, 4><<<(N + 31) / 32, 256, 0, stream>>>(bufB, W2, bufA, N);
    k_gather2<<<(N + 3) / 4, 256, 0, stream>>>(bufA, row_ptr, csr, dinv, b2, Wfc, bfc, out, N);
}

// Round 4
// 591.250 us; speedup vs baseline: 3.8606x; 1.1662x over previous
//
#include <hip/hip_runtime.h>

#define NN 100000
#define NRANGE 8
#define RANGE_SZ (NN / NRANGE)   // 12500 exactly

// ---- detect whether edge_index is int64 (hi words all zero) or int32 ----
__global__ __launch_bounds__(64) void k_detect(const unsigned int* ei, int* flag) {
    if (threadIdx.x == 0) {
        int is64 = 1;
        for (int i = 0; i < 64; ++i)
            if (ei[2 * i + 1] != 0u) { is64 = 0; break; }
        *flag = is64;
    }
}

__global__ __launch_bounds__(256) void k_hist(const int* __restrict__ ei32,
                                              const long long* __restrict__ ei64,
                                              const int* __restrict__ flag,
                                              int E, int* __restrict__ degi) {
    int e = blockIdx.x * 256 + threadIdx.x;
    if (e >= E) return;
    int dst = (*flag) ? (int)ei64[(long long)E + e] : ei32[E + e];
    atomicAdd(&degi[dst], 1);
}

// ---- 3-step exclusive scan of degi -> row_ptr, cursor, dinv ----
__global__ __launch_bounds__(256) void k_scan1(const int* __restrict__ degi,
                                               int* __restrict__ bsum, int n) {
    __shared__ int s[256];
    int t = threadIdx.x;
    int i = blockIdx.x * 256 + t;
    s[t] = (i < n) ? degi[i] : 0;
    __syncthreads();
    for (int off = 128; off; off >>= 1) {
        if (t < off) s[t] += s[t + off];
        __syncthreads();
    }
    if (t == 0) bsum[blockIdx.x] = s[0];
}

__global__ __launch_bounds__(512) void k_scan2(int* __restrict__ bsum, int nb,
                                               int* __restrict__ row_ptr, int n, int E) {
    __shared__ int s[512];
    int t = threadIdx.x;
    int v = (t < nb) ? bsum[t] : 0;
    s[t] = v;
    __syncthreads();
    for (int off = 1; off < 512; off <<= 1) {
        int add = (t >= off) ? s[t - off] : 0;
        __syncthreads();
        s[t] += add;
        __syncthreads();
    }
    if (t < nb) bsum[t] = s[t] - v;  // exclusive
    if (t == 0) row_ptr[n] = E;
}

__global__ __launch_bounds__(256) void k_scan3(const int* __restrict__ degi,
                                               const int* __restrict__ bsum,
                                               int* __restrict__ row_ptr,
                                               int* __restrict__ cursor,
                                               float* __restrict__ dinv, int n) {
    __shared__ int s[256];
    int t = threadIdx.x;
    int i = blockIdx.x * 256 + t;
    int v = (i < n) ? degi[i] : 0;
    s[t] = v;
    __syncthreads();
    for (int off = 1; off < 256; off <<= 1) {
        int add = (t >= off) ? s[t - off] : 0;
        __syncthreads();
        s[t] += add;
        __syncthreads();
    }
    int row = bsum[blockIdx.x] + s[t] - v;  // exclusive
    if (i < n) {
        row_ptr[i] = row;
        cursor[i] = row;
        dinv[i] = rsqrtf((float)v + 1.0f);
    }
}

// ---- CSR fill, dst-range partitioned so csr-store locality is per-XCD ----
__global__ __launch_bounds__(256) void k_fill(const int* __restrict__ ei32,
                                              const long long* __restrict__ ei64,
                                              const int* __restrict__ flag,
                                              int E, int nchunks,
                                              int* __restrict__ cursor,
                                              int* __restrict__ csr) {
    int r = blockIdx.x & (NRANGE - 1);
    int chunk = blockIdx.x >> 3;
    int per = (E + nchunks - 1) / nchunks;
    int beg = chunk * per;
    int end = min(beg + per, E);
    int lo = r * RANGE_SZ, hi = lo + RANGE_SZ;
    bool is64 = (*flag) != 0;
    for (int e = beg + (int)threadIdx.x; e < end; e += 256) {
        int dst = is64 ? (int)ei64[(long long)E + e] : ei32[E + e];
        if (dst >= lo && dst < hi) {
            int src = is64 ? (int)ei64[e] : ei32[e];
            int slot = atomicAdd(&cursor[dst], 1);
            csr[slot] = src;
        }
    }
}

// ---- skinny GEMM: H[N,C] = X[N,K] @ W[K,C]; optional row-scale by dinv ----
template <int K, int C, int RPT, bool SCALE>
__global__ __launch_bounds__(256) void k_gemm(const float* __restrict__ X,
                                              const float* __restrict__ W,
                                              const float* __restrict__ dinv,
                                              float* __restrict__ H, int n) {
    constexpr int CG = C / 4;
    constexpr int RS = 256 / CG;
    constexpr int RT = RS * RPT;
    constexpr int XS = K + 4;
    __shared__ float Ws[K * C];
    __shared__ float Xs[RT * XS];
    const int t = threadIdx.x;

    for (int i = t * 4; i < K * C; i += 1024)
        *(float4*)&Ws[i] = *(const float4*)&W[i];

    const int row0 = blockIdx.x * RT;
    for (int i = t * 4; i < RT * K; i += 1024) {
        int r = i / K, k = i % K;
        int gr = row0 + r;
        float4 v = make_float4(0.f, 0.f, 0.f, 0.f);
        if (gr < n) v = *(const float4*)&X[(long long)gr * K + k];
        *(float4*)&Xs[r * XS + k] = v;
    }
    __syncthreads();

    const int cg = t % CG, rs = t / CG;
    float acc[RPT][4];
#pragma unroll
    for (int i = 0; i < RPT; ++i)
#pragma unroll
        for (int j = 0; j < 4; ++j) acc[i][j] = 0.f;

#pragma unroll 4
    for (int k = 0; k < K; ++k) {
        float4 w = *(float4*)&Ws[k * C + cg * 4];
#pragma unroll
        for (int i = 0; i < RPT; ++i) {
            float xv = Xs[(rs * RPT + i) * XS + k];
            acc[i][0] = fmaf(xv, w.x, acc[i][0]);
            acc[i][1] = fmaf(xv, w.y, acc[i][1]);
            acc[i][2] = fmaf(xv, w.z, acc[i][2]);
            acc[i][3] = fmaf(xv, w.w, acc[i][3]);
        }
    }
#pragma unroll
    for (int i = 0; i < RPT; ++i) {
        int gr = row0 + rs * RPT + i;
        if (gr < n) {
            float sc = SCALE ? dinv[gr] : 1.f;
            *(float4*)&H[(long long)gr * C + cg * 4] =
                make_float4(acc[i][0] * sc, acc[i][1] * sc, acc[i][2] * sc, acc[i][3] * sc);
        }
    }
}

// ---- gather (F=64): acc = sum of pre-scaled rows + self; wave per node ----
// RELU=1: out = relu(d*acc + bias)*d   (layer-1 output, pre-scaled for layer 2)
// RELU=0: out = d*acc                  (layer-2 aggregation, feeds gemm2fc)
template <bool RELU>
__global__ __launch_bounds__(256) void k_gather(const float* __restrict__ h,
                                                const int* __restrict__ row_ptr,
                                                const int* __restrict__ csr,
                                                const float* __restrict__ dinv,
                                                const float* __restrict__ bias,
                                                float* __restrict__ out, int n) {
    int node = blockIdx.x * 4 + (threadIdx.x >> 6);
    int lane = threadIdx.x & 63;
    if (node >= n) return;
    float d = dinv[node];
    int beg = row_ptr[node], end = row_ptr[node + 1];
    float a0 = 0.f, a1 = 0.f;
    int i = beg;
    for (; i + 3 < end; i += 4) {
        int s0 = csr[i], s1 = csr[i + 1], s2 = csr[i + 2], s3 = csr[i + 3];
        float x0 = h[(long long)s0 * 64 + lane];
        float x1 = h[(long long)s1 * 64 + lane];
        float x2 = h[(long long)s2 * 64 + lane];
        float x3 = h[(long long)s3 * 64 + lane];
        a0 += x0;
        a1 += x1;
        a0 += x2;
        a1 += x3;
    }
    for (; i < end; ++i) a0 += h[(long long)csr[i] * 64 + lane];
    float acc = a0 + a1 + h[(long long)node * 64 + lane];
    float v;
    if (RELU)
        v = fmaxf(fmaf(d, acc, bias[lane]), 0.f) * d;
    else
        v = d * acc;
    out[(long long)node * 64 + lane] = v;
}

// ---- fused: out[row] = relu(G[row]@W2 + b2) . Wfc + bfc ----
__global__ __launch_bounds__(256) void k_gemm2fc(const float* __restrict__ G,
                                                 const float* __restrict__ W2,
                                                 const float* __restrict__ b2,
                                                 const float* __restrict__ Wfc,
                                                 const float* __restrict__ bfc,
                                                 float* __restrict__ out, int n) {
    constexpr int K = 64, C = 128, CG = 32, RPT = 4, RT = 32, XS = K + 4;
    __shared__ float Ws[K * C];
    __shared__ float Xs[RT * XS];
    const int t = threadIdx.x;

    for (int i = t * 4; i < K * C; i += 1024)
        *(float4*)&Ws[i] = *(const float4*)&W2[i];

    const int row0 = blockIdx.x * RT;
    for (int i = t * 4; i < RT * K; i += 1024) {
        int r = i / K, k = i % K;
        int gr = row0 + r;
        float4 v = make_float4(0.f, 0.f, 0.f, 0.f);
        if (gr < n) v = *(const float4*)&G[(long long)gr * K + k];
        *(float4*)&Xs[r * XS + k] = v;
    }
    __syncthreads();

    const int cg = t % CG, rs = t / CG;
    float acc[RPT][4];
#pragma unroll
    for (int i = 0; i < RPT; ++i)
#pragma unroll
        for (int j = 0; j < 4; ++j) acc[i][j] = 0.f;

#pragma unroll 4
    for (int k = 0; k < K; ++k) {
        float4 w = *(float4*)&Ws[k * C + cg * 4];
#pragma unroll
        for (int i = 0; i < RPT; ++i) {
            float xv = Xs[(rs * RPT + i) * XS + k];
            acc[i][0] = fmaf(xv, w.x, acc[i][0]);
            acc[i][1] = fmaf(xv, w.y, acc[i][1]);
            acc[i][2] = fmaf(xv, w.z, acc[i][2]);
            acc[i][3] = fmaf(xv, w.w, acc[i][3]);
        }
    }

    float4 bv = *(const float4*)&b2[cg * 4];
    float4 wf = *(const float4*)&Wfc[cg * 4];
#pragma unroll
    for (int i = 0; i < RPT; ++i) {
        float p = fmaxf(acc[i][0] + bv.x, 0.f) * wf.x
                + fmaxf(acc[i][1] + bv.y, 0.f) * wf.y
                + fmaxf(acc[i][2] + bv.z, 0.f) * wf.z
                + fmaxf(acc[i][3] + bv.w, 0.f) * wf.w;
#pragma unroll
        for (int off = 16; off; off >>= 1) p += __shfl_down(p, off, 32);
        int gr = row0 + rs * RPT + i;
        if (cg == 0 && gr < n) out[gr] = p + bfc[0];
    }
}

extern "C" void kernel_launch(void* const* d_in, const int* in_sizes, int n_in,
                              void* d_out, int out_size, void* d_ws, size_t ws_size,
                              hipStream_t stream) {
    const float* x   = (const float*)d_in[0];
    const void*  ei  = d_in[1];
    const float* W1  = (const float*)d_in[2];
    const float* b1  = (const float*)d_in[3];
    const float* W2  = (const float*)d_in[4];
    const float* b2  = (const float*)d_in[5];
    const float* Wfc = (const float*)d_in[6];
    const float* bfc = (const float*)d_in[7];
    float* out = (float*)d_out;

    const int N = NN;
    const int E = in_sizes[1] / 2;
    const int NB = (N + 255) / 256;

    char* ws = (char*)d_ws;
    size_t o = 0;
    auto carve = [&](size_t bytes) {
        char* p = ws + o;
        o = (o + bytes + 255) & ~(size_t)255;
        return p;
    };
    int*   degi    = (int*)carve((size_t)N * 4);
    float* dinv    = (float*)carve((size_t)N * 4);
    int*   row_ptr = (int*)carve((size_t)(N + 1) * 4);
    int*   cursor  = (int*)carve((size_t)N * 4);
    int*   bsum    = (int*)carve((size_t)NB * 4);
    int*   flag    = (int*)carve(4);
    int*   csr     = (int*)carve((size_t)E * 4);
    float* bufA    = (float*)carve((size_t)N * 64 * 4);   // h1s, then g2
    float* bufB    = (float*)carve((size_t)N * 64 * 4);   // h1rs

    const int* ei32 = (const int*)ei;
    const long long* ei64 = (const long long*)ei;

    // ---- degree + dinv + CSR build (shared by both layers) ----
    hipMemsetAsync(degi, 0, (size_t)N * 4, stream);
    k_detect<<<1, 64, 0, stream>>>((const unsigned int*)ei, flag);
    k_hist<<<(E + 255) / 256, 256, 0, stream>>>(ei32, ei64, flag, E, degi);
    k_scan1<<<NB, 256, 0, stream>>>(degi, bsum, N);
    k_scan2<<<1, 512, 0, stream>>>(bsum, NB, row_ptr, N, E);
    k_scan3<<<NB, 256, 0, stream>>>(degi, bsum, row_ptr, cursor, dinv, N);
    const int NCHUNK = 256;
    k_fill<<<NCHUNK * NRANGE, 256, 0, stream>>>(ei32, ei64, flag, E, NCHUNK, cursor, csr);

    // ---- layer 1: h1s = (x @ W1) * dinv[row]  -> bufA ----
    k_gemm<128, 64, 2, true><<<(N + 31) / 32, 256, 0, stream>>>(x, W1, dinv, bufA, N);
    // h1rs = relu(d*(sum + self) + b1) * d  -> bufB
    k_gather<true><<<(N + 3) / 4, 256, 0, stream>>>(bufA, row_ptr, csr, dinv, b1, bufB, N);

    // ---- layer 2: g2 = d*(sum + self) of h1rs  -> bufA (reuse) ----
    k_gather<false><<<(N + 3) / 4, 256, 0, stream>>>(bufB, row_ptr, csr, dinv, nullptr, bufA, N);
    // out = relu(g2 @ W2 + b2) . Wfc + bfc
    k_gemm2fc<<<(N + 31) / 32, 256, 0, stream>>>(bufA, W2, b2, Wfc, bfc, out, N);
}

// Round 5
// 561.626 us; speedup vs baseline: 4.0643x; 1.0527x over previous
//
#include <hip/hip_runtime.h>
#include <hip/hip_fp16.h>

#define NN 100000
#define NRANGE 8
#define RANGE_SZ (NN / NRANGE)   // 12500 exactly

// ---- detect whether edge_index is int64 (hi words all zero) or int32 ----
__global__ __launch_bounds__(64) void k_detect(const unsigned int* ei, int* flag) {
    if (threadIdx.x == 0) {
        int is64 = 1;
        for (int i = 0; i < 64; ++i)
            if (ei[2 * i + 1] != 0u) { is64 = 0; break; }
        *flag = is64;
    }
}

// values < 2^31, little-endian: low dword of an int64 element j is ei_lo[2*j].
// stride s = 2 (int64) or 1 (int32); element j -> ei_lo[s*j].
__global__ __launch_bounds__(256) void k_hist(const int* __restrict__ ei_lo,
                                              const int* __restrict__ flag,
                                              int E, int* __restrict__ degi) {
    int e = blockIdx.x * 256 + threadIdx.x;
    if (e >= E) return;
    int s = (*flag) ? 2 : 1;
    int dst = __builtin_nontemporal_load(&ei_lo[(long long)s * (E + e)]);
    atomicAdd(&degi[dst], 1);
}

// ---- 3-step exclusive scan of degi -> row_ptr, cursor, dinv ----
__global__ __launch_bounds__(256) void k_scan1(const int* __restrict__ degi,
                                               int* __restrict__ bsum, int n) {
    __shared__ int s[256];
    int t = threadIdx.x;
    int i = blockIdx.x * 256 + t;
    s[t] = (i < n) ? degi[i] : 0;
    __syncthreads();
    for (int off = 128; off; off >>= 1) {
        if (t < off) s[t] += s[t + off];
        __syncthreads();
    }
    if (t == 0) bsum[blockIdx.x] = s[0];
}

__global__ __launch_bounds__(512) void k_scan2(int* __restrict__ bsum, int nb,
                                               int* __restrict__ row_ptr, int n, int E) {
    __shared__ int s[512];
    int t = threadIdx.x;
    int v = (t < nb) ? bsum[t] : 0;
    s[t] = v;
    __syncthreads();
    for (int off = 1; off < 512; off <<= 1) {
        int add = (t >= off) ? s[t - off] : 0;
        __syncthreads();
        s[t] += add;
        __syncthreads();
    }
    if (t < nb) bsum[t] = s[t] - v;  // exclusive
    if (t == 0) row_ptr[n] = E;
}

__global__ __launch_bounds__(256) void k_scan3(const int* __restrict__ degi,
                                               const int* __restrict__ bsum,
                                               int* __restrict__ row_ptr,
                                               int* __restrict__ cursor,
                                               float* __restrict__ dinv, int n) {
    __shared__ int s[256];
    int t = threadIdx.x;
    int i = blockIdx.x * 256 + t;
    int v = (i < n) ? degi[i] : 0;
    s[t] = v;
    __syncthreads();
    for (int off = 1; off < 256; off <<= 1) {
        int add = (t >= off) ? s[t - off] : 0;
        __syncthreads();
        s[t] += add;
        __syncthreads();
    }
    int row = bsum[blockIdx.x] + s[t] - v;  // exclusive
    if (i < n) {
        row_ptr[i] = row;
        cursor[i] = row;
        dinv[i] = rsqrtf((float)v + 1.0f);
    }
}

// ---- CSR fill, dst-range partitioned (csr store locality per XCD),
//      edge stream via non-temporal loads to keep csr lines resident in L2 ----
__global__ __launch_bounds__(256) void k_fill(const int* __restrict__ ei_lo,
                                              const int* __restrict__ flag,
                                              int E, int nchunks,
                                              int* __restrict__ cursor,
                                              int* __restrict__ csr) {
    int r = blockIdx.x & (NRANGE - 1);
    int chunk = blockIdx.x >> 3;
    int per = (E + nchunks - 1) / nchunks;
    int beg = chunk * per;
    int end = min(beg + per, E);
    int lo = r * RANGE_SZ, hi = lo + RANGE_SZ;
    int s = (*flag) ? 2 : 1;
    for (int e = beg + (int)threadIdx.x; e < end; e += 256) {
        int dst = __builtin_nontemporal_load(&ei_lo[(long long)s * (E + e)]);
        if (dst >= lo && dst < hi) {
            int src = __builtin_nontemporal_load(&ei_lo[(long long)s * e]);
            int slot = atomicAdd(&cursor[dst], 1);
            csr[slot] = src;
        }
    }
}

// ---- GEMM1: H[N,64] = (X[N,128] @ W[128,64]) * dinv[row], fp16 out ----
__global__ __launch_bounds__(256) void k_gemm1(const float* __restrict__ X,
                                               const float* __restrict__ W,
                                               const float* __restrict__ dinv,
                                               __half* __restrict__ H, int n) {
    constexpr int K = 128, C = 64, RPT = 2;
    constexpr int CG = C / 4, RS = 256 / CG, RT = RS * RPT, XS = K + 4;
    __shared__ float Ws[K * C];
    __shared__ float Xs[RT * XS];
    const int t = threadIdx.x;

    for (int i = t * 4; i < K * C; i += 1024)
        *(float4*)&Ws[i] = *(const float4*)&W[i];

    const int row0 = blockIdx.x * RT;
    for (int i = t * 4; i < RT * K; i += 1024) {
        int r = i / K, k = i % K;
        int gr = row0 + r;
        float4 v = make_float4(0.f, 0.f, 0.f, 0.f);
        if (gr < n) v = *(const float4*)&X[(long long)gr * K + k];
        *(float4*)&Xs[r * XS + k] = v;
    }
    __syncthreads();

    const int cg = t % CG, rs = t / CG;
    float acc[RPT][4];
#pragma unroll
    for (int i = 0; i < RPT; ++i)
#pragma unroll
        for (int j = 0; j < 4; ++j) acc[i][j] = 0.f;

#pragma unroll 4
    for (int k = 0; k < K; ++k) {
        float4 w = *(float4*)&Ws[k * C + cg * 4];
#pragma unroll
        for (int i = 0; i < RPT; ++i) {
            float xv = Xs[(rs * RPT + i) * XS + k];
            acc[i][0] = fmaf(xv, w.x, acc[i][0]);
            acc[i][1] = fmaf(xv, w.y, acc[i][1]);
            acc[i][2] = fmaf(xv, w.z, acc[i][2]);
            acc[i][3] = fmaf(xv, w.w, acc[i][3]);
        }
    }
#pragma unroll
    for (int i = 0; i < RPT; ++i) {
        int gr = row0 + rs * RPT + i;
        if (gr < n) {
            float sc = dinv[gr];
            union { __half h[4]; uint2 u; } pk;
            pk.h[0] = __float2half(acc[i][0] * sc);
            pk.h[1] = __float2half(acc[i][1] * sc);
            pk.h[2] = __float2half(acc[i][2] * sc);
            pk.h[3] = __float2half(acc[i][3] * sc);
            *(uint2*)&H[(long long)gr * C + cg * 4] = pk.u;
        }
    }
}

// ---- gather (F=64, fp16 rows, fp32 accum): wave per node ----
// RELU=1: out(half) = relu(d*acc + bias)*d ; RELU=0: out(float) = d*acc
template <bool RELU>
__global__ __launch_bounds__(256) void k_gather(const __half* __restrict__ h,
                                                const int* __restrict__ row_ptr,
                                                const int* __restrict__ csr,
                                                const float* __restrict__ dinv,
                                                const float* __restrict__ bias,
                                                void* __restrict__ outv, int n) {
    int node = blockIdx.x * 4 + (threadIdx.x >> 6);
    int lane = threadIdx.x & 63;
    if (node >= n) return;
    float d = dinv[node];
    int beg = row_ptr[node], end = row_ptr[node + 1];
    float a0 = 0.f, a1 = 0.f;
    int i = beg;
    for (; i + 3 < end; i += 4) {
        int s0 = csr[i], s1 = csr[i + 1], s2 = csr[i + 2], s3 = csr[i + 3];
        float x0 = __half2float(h[(long long)s0 * 64 + lane]);
        float x1 = __half2float(h[(long long)s1 * 64 + lane]);
        float x2 = __half2float(h[(long long)s2 * 64 + lane]);
        float x3 = __half2float(h[(long long)s3 * 64 + lane]);
        a0 += x0;
        a1 += x1;
        a0 += x2;
        a1 += x3;
    }
    for (; i < end; ++i) a0 += __half2float(h[(long long)csr[i] * 64 + lane]);
    float acc = a0 + a1 + __half2float(h[(long long)node * 64 + lane]);
    if (RELU) {
        float v = fmaxf(fmaf(d, acc, bias[lane]), 0.f) * d;
        ((__half*)outv)[(long long)node * 64 + lane] = __float2half(v);
    } else {
        ((float*)outv)[(long long)node * 64 + lane] = d * acc;
    }
}

// ---- fused: out[row] = relu(G[row]@W2 + b2) . Wfc + bfc ----
__global__ __launch_bounds__(256) void k_gemm2fc(const float* __restrict__ G,
                                                 const float* __restrict__ W2,
                                                 const float* __restrict__ b2,
                                                 const float* __restrict__ Wfc,
                                                 const float* __restrict__ bfc,
                                                 float* __restrict__ out, int n) {
    constexpr int K = 64, C = 128, CG = 32, RPT = 4, RT = 32, XS = K + 4;
    __shared__ float Ws[K * C];
    __shared__ float Xs[RT * XS];
    const int t = threadIdx.x;

    for (int i = t * 4; i < K * C; i += 1024)
        *(float4*)&Ws[i] = *(const float4*)&W2[i];

    const int row0 = blockIdx.x * RT;
    for (int i = t * 4; i < RT * K; i += 1024) {
        int r = i / K, k = i % K;
        int gr = row0 + r;
        float4 v = make_float4(0.f, 0.f, 0.f, 0.f);
        if (gr < n) v = *(const float4*)&G[(long long)gr * K + k];
        *(float4*)&Xs[r * XS + k] = v;
    }
    __syncthreads();

    const int cg = t % CG, rs = t / CG;
    float acc[RPT][4];
#pragma unroll
    for (int i = 0; i < RPT; ++i)
#pragma unroll
        for (int j = 0; j < 4; ++j) acc[i][j] = 0.f;

#pragma unroll 4
    for (int k = 0; k < K; ++k) {
        float4 w = *(float4*)&Ws[k * C + cg * 4];
#pragma unroll
        for (int i = 0; i < RPT; ++i) {
            float xv = Xs[(rs * RPT + i) * XS + k];
            acc[i][0] = fmaf(xv, w.x, acc[i][0]);
            acc[i][1] = fmaf(xv, w.y, acc[i][1]);
            acc[i][2] = fmaf(xv, w.z, acc[i][2]);
            acc[i][3] = fmaf(xv, w.w, acc[i][3]);
        }
    }

    float4 bv = *(const float4*)&b2[cg * 4];
    float4 wf = *(const float4*)&Wfc[cg * 4];
#pragma unroll
    for (int i = 0; i < RPT; ++i) {
        float p = fmaxf(acc[i][0] + bv.x, 0.f) * wf.x
                + fmaxf(acc[i][1] + bv.y, 0.f) * wf.y
                + fmaxf(acc[i][2] + bv.z, 0.f) * wf.z
                + fmaxf(acc[i][3] + bv.w, 0.f) * wf.w;
#pragma unroll
        for (int off = 16; off; off >>= 1) p += __shfl_down(p, off, 32);
        int gr = row0 + rs * RPT + i;
        if (cg == 0 && gr < n) out[gr] = p + bfc[0];
    }
}

extern "C" void kernel_launch(void* const* d_in, const int* in_sizes, int n_in,
                              void* d_out, int out_size, void* d_ws, size_t ws_size,
                              hipStream_t stream) {
    const float* x   = (const float*)d_in[0];
    const void*  ei  = d_in[1];
    const float* W1  = (const float*)d_in[2];
    const float* b1  = (const float*)d_in[3];
    const float* W2  = (const float*)d_in[4];
    const float* b2  = (const float*)d_in[5];
    const float* Wfc = (const float*)d_in[6];
    const float* bfc = (const float*)d_in[7];
    float* out = (float*)d_out;

    const int N = NN;
    const int E = in_sizes[1] / 2;
    const int NB = (N + 255) / 256;

    char* ws = (char*)d_ws;
    size_t o = 0;
    auto carve = [&](size_t bytes) {
        char* p = ws + o;
        o = (o + bytes + 255) & ~(size_t)255;
        return p;
    };
    int*    degi    = (int*)carve((size_t)N * 4);
    float*  dinv    = (float*)carve((size_t)N * 4);
    int*    row_ptr = (int*)carve((size_t)(N + 1) * 4);
    int*    cursor  = (int*)carve((size_t)N * 4);
    int*    bsum    = (int*)carve((size_t)NB * 4);
    int*    flag    = (int*)carve(4);
    int*    csr     = (int*)carve((size_t)E * 4);
    __half* bufA    = (__half*)carve((size_t)N * 64 * 2);   // h1s (fp16)
    __half* bufB    = (__half*)carve((size_t)N * 64 * 2);   // h1rs (fp16)
    float*  bufG    = (float*)carve((size_t)N * 64 * 4);    // g2 (fp32)

    const int* ei_lo = (const int*)ei;

    // ---- degree + dinv + CSR build (shared by both layers) ----
    hipMemsetAsync(degi, 0, (size_t)N * 4, stream);
    k_detect<<<1, 64, 0, stream>>>((const unsigned int*)ei, flag);
    k_hist<<<(E + 255) / 256, 256, 0, stream>>>(ei_lo, flag, E, degi);
    k_scan1<<<NB, 256, 0, stream>>>(degi, bsum, N);
    k_scan2<<<1, 512, 0, stream>>>(bsum, NB, row_ptr, N, E);
    k_scan3<<<NB, 256, 0, stream>>>(degi, bsum, row_ptr, cursor, dinv, N);
    const int NCHUNK = 256;
    k_fill<<<NCHUNK * NRANGE, 256, 0, stream>>>(ei_lo, flag, E, NCHUNK, cursor, csr);

    // ---- layer 1: h1s = (x @ W1) * dinv[row]  -> bufA (fp16) ----
    k_gemm1<<<(N + 31) / 32, 256, 0, stream>>>(x, W1, dinv, bufA, N);
    // h1rs = relu(d*(sum + self) + b1) * d  -> bufB (fp16)
    k_gather<true><<<(N + 3) / 4, 256, 0, stream>>>(bufA, row_ptr, csr, dinv, b1, bufB, N);

    // ---- layer 2: g2 = d*(sum + self) of h1rs  -> bufG (fp32) ----
    k_gather<false><<<(N + 3) / 4, 256, 0, stream>>>(bufB, row_ptr, csr, dinv, nullptr, bufG, N);
    // out = relu(g2 @ W2 + b2) . Wfc + bfc
    k_gemm2fc<<<(N + 31) / 32, 256, 0, stream>>>(bufG, W2, b2, Wfc, bfc, out, N);
}

// Round 6
// 365.186 us; speedup vs baseline: 6.2505x; 1.5379x over previous
//
#include <hip/hip_runtime.h>
#include <hip/hip_fp16.h>

#define NN 100000
#define NBIN 128
#define RANGE 782            // ceil(100000/128); 128*782 = 100096 >= 100000
#define CAP 32768            // per-bin capacity (expected ~25e3, sigma ~160)

// ---- detect whether edge_index is int64 (hi words all zero) or int32 ----
__global__ __launch_bounds__(64) void k_detect(const unsigned int* ei, int* flag) {
    if (threadIdx.x == 0) {
        int is64 = 1;
        for (int i = 0; i < 64; ++i)
            if (ei[2 * i + 1] != 0u) { is64 = 0; break; }
        *flag = is64;
    }
}

// ---- pass A: block-level radix scatter of edges into 128 dst-bins ----
// stores are append-chunks (~256B runs) -> near-1x write amplification.
__global__ __launch_bounds__(256) void k_binA(const int* __restrict__ ei_lo,
                                              const int* __restrict__ flag,
                                              int E, int* __restrict__ g_bincnt,
                                              uint2* __restrict__ binbuf) {
    constexpr int ITER = 16;
    __shared__ int cnt[NBIN], basep[NBIN], pos[NBIN];
    const int t = threadIdx.x;
    const int base = blockIdx.x * (256 * ITER);
    const int s = (*flag) ? 2 : 1;
    uint2 ed[ITER];
    int bn[ITER];

    for (int i = t; i < NBIN; i += 256) { cnt[i] = 0; pos[i] = 0; }
    __syncthreads();

#pragma unroll
    for (int i = 0; i < ITER; ++i) {
        int e = base + i * 256 + t;
        if (e < E) {
            int src = __builtin_nontemporal_load(&ei_lo[(long long)s * e]);
            int dst = __builtin_nontemporal_load(&ei_lo[(long long)s * (E + e)]);
            ed[i] = make_uint2((unsigned)src, (unsigned)dst);
            bn[i] = dst / RANGE;
            atomicAdd(&cnt[bn[i]], 1);
        } else bn[i] = -1;
    }
    __syncthreads();
    for (int i = t; i < NBIN; i += 256)
        basep[i] = atomicAdd(&g_bincnt[i], cnt[i]);
    __syncthreads();
#pragma unroll
    for (int i = 0; i < ITER; ++i) {
        if (bn[i] >= 0) {
            int r = atomicAdd(&pos[bn[i]], 1);
            binbuf[(long long)bn[i] * CAP + basep[bn[i]] + r] = ed[i];
        }
    }
}

// ---- tiny scan of the 128 bin counts -> bin starts; also row_ptr[N]=E ----
__global__ __launch_bounds__(64) void k_scanbin(const int* __restrict__ g_bincnt,
                                                int* __restrict__ g_binstart,
                                                int* __restrict__ row_ptr, int n, int E) {
    if (threadIdx.x == 0) {
        int run = 0;
        for (int b = 0; b < NBIN; ++b) { g_binstart[b] = run; run += g_bincnt[b]; }
        row_ptr[n] = E;
    }
}

// ---- pass B: one block per bin. LDS histogram -> row_ptr/dinv,
//      then LDS-cursor scatter into csr (no global atomics). ----
__global__ __launch_bounds__(512) void k_build(const uint2* __restrict__ binbuf,
                                               const int* __restrict__ g_bincnt,
                                               const int* __restrict__ g_binstart,
                                               int* __restrict__ row_ptr,
                                               float* __restrict__ dinv,
                                               int* __restrict__ csr, int n) {
    __shared__ int cnt[1024];
    __shared__ int ssum[512];
    const int t = threadIdx.x;
    const int bin = blockIdx.x;
    const int lo = bin * RANGE;
    const int rn = min(RANGE, n - lo);
    const int nE = g_bincnt[bin];
    const int bstart = g_binstart[bin];
    const uint2* __restrict__ src = binbuf + (long long)bin * CAP;

    cnt[t] = 0; cnt[t + 512] = 0;
    __syncthreads();
    for (int i = t; i < nE; i += 512) {
        uint2 e = src[i];
        atomicAdd(&cnt[(int)e.y - lo], 1);
    }
    __syncthreads();
    int a = cnt[2 * t], b = cnt[2 * t + 1];
    ssum[t] = a + b;
    __syncthreads();
    for (int off = 1; off < 512; off <<= 1) {
        int add = (t >= off) ? ssum[t - off] : 0;
        __syncthreads();
        ssum[t] += add;
        __syncthreads();
    }
    int prev = (t > 0) ? ssum[t - 1] : 0;  // exclusive over pairs
    cnt[2 * t] = prev;                      // cursor (relative slot)
    cnt[2 * t + 1] = prev + a;
    if (2 * t < rn) {
        row_ptr[lo + 2 * t] = bstart + prev;
        dinv[lo + 2 * t] = rsqrtf((float)a + 1.f);
    }
    if (2 * t + 1 < rn) {
        row_ptr[lo + 2 * t + 1] = bstart + prev + a;
        dinv[lo + 2 * t + 1] = rsqrtf((float)b + 1.f);
    }
    __syncthreads();
    for (int i = t; i < nE; i += 512) {
        uint2 e = src[i];
        int slot = bstart + atomicAdd(&cnt[(int)e.y - lo], 1);
        csr[slot] = (int)e.x;
    }
}

// ---- GEMM1: H[N,64] = (X[N,128] @ W[128,64]) * dinv[row], fp16 out ----
__global__ __launch_bounds__(256) void k_gemm1(const float* __restrict__ X,
                                               const float* __restrict__ W,
                                               const float* __restrict__ dinv,
                                               __half* __restrict__ H, int n) {
    constexpr int K = 128, C = 64, RPT = 2;
    constexpr int CG = C / 4, RS = 256 / CG, RT = RS * RPT, XS = K + 4;
    __shared__ float Ws[K * C];
    __shared__ float Xs[RT * XS];
    const int t = threadIdx.x;

    for (int i = t * 4; i < K * C; i += 1024)
        *(float4*)&Ws[i] = *(const float4*)&W[i];

    const int row0 = blockIdx.x * RT;
    for (int i = t * 4; i < RT * K; i += 1024) {
        int r = i / K, k = i % K;
        int gr = row0 + r;
        float4 v = make_float4(0.f, 0.f, 0.f, 0.f);
        if (gr < n) v = *(const float4*)&X[(long long)gr * K + k];
        *(float4*)&Xs[r * XS + k] = v;
    }
    __syncthreads();

    const int cg = t % CG, rs = t / CG;
    float acc[RPT][4];
#pragma unroll
    for (int i = 0; i < RPT; ++i)
#pragma unroll
        for (int j = 0; j < 4; ++j) acc[i][j] = 0.f;

#pragma unroll 4
    for (int k = 0; k < K; ++k) {
        float4 w = *(float4*)&Ws[k * C + cg * 4];
#pragma unroll
        for (int i = 0; i < RPT; ++i) {
            float xv = Xs[(rs * RPT + i) * XS + k];
            acc[i][0] = fmaf(xv, w.x, acc[i][0]);
            acc[i][1] = fmaf(xv, w.y, acc[i][1]);
            acc[i][2] = fmaf(xv, w.z, acc[i][2]);
            acc[i][3] = fmaf(xv, w.w, acc[i][3]);
        }
    }
#pragma unroll
    for (int i = 0; i < RPT; ++i) {
        int gr = row0 + rs * RPT + i;
        if (gr < n) {
            float sc = dinv[gr];
            union { __half h[4]; uint2 u; } pk;
            pk.h[0] = __float2half(acc[i][0] * sc);
            pk.h[1] = __float2half(acc[i][1] * sc);
            pk.h[2] = __float2half(acc[i][2] * sc);
            pk.h[3] = __float2half(acc[i][3] * sc);
            *(uint2*)&H[(long long)gr * C + cg * 4] = pk.u;
        }
    }
}

// ---- gather (F=64, fp16 rows, fp32 accum): wave per node ----
template <bool RELU>
__global__ __launch_bounds__(256) void k_gather(const __half* __restrict__ h,
                                                const int* __restrict__ row_ptr,
                                                const int* __restrict__ csr,
                                                const float* __restrict__ dinv,
                                                const float* __restrict__ bias,
                                                void* __restrict__ outv, int n) {
    int node = blockIdx.x * 4 + (threadIdx.x >> 6);
    int lane = threadIdx.x & 63;
    if (node >= n) return;
    float d = dinv[node];
    int beg = row_ptr[node], end = row_ptr[node + 1];
    float a0 = 0.f, a1 = 0.f;
    int i = beg;
    for (; i + 3 < end; i += 4) {
        int s0 = csr[i], s1 = csr[i + 1], s2 = csr[i + 2], s3 = csr[i + 3];
        float x0 = __half2float(h[(long long)s0 * 64 + lane]);
        float x1 = __half2float(h[(long long)s1 * 64 + lane]);
        float x2 = __half2float(h[(long long)s2 * 64 + lane]);
        float x3 = __half2float(h[(long long)s3 * 64 + lane]);
        a0 += x0;
        a1 += x1;
        a0 += x2;
        a1 += x3;
    }
    for (; i < end; ++i) a0 += __half2float(h[(long long)csr[i] * 64 + lane]);
    float acc = a0 + a1 + __half2float(h[(long long)node * 64 + lane]);
    if (RELU) {
        float v = fmaxf(fmaf(d, acc, bias[lane]), 0.f) * d;
        ((__half*)outv)[(long long)node * 64 + lane] = __float2half(v);
    } else {
        ((float*)outv)[(long long)node * 64 + lane] = d * acc;
    }
}

// ---- fused: out[row] = relu(G[row]@W2 + b2) . Wfc + bfc ----
__global__ __launch_bounds__(256) void k_gemm2fc(const float* __restrict__ G,
                                                 const float* __restrict__ W2,
                                                 const float* __restrict__ b2,
                                                 const float* __restrict__ Wfc,
                                                 const float* __restrict__ bfc,
                                                 float* __restrict__ out, int n) {
    constexpr int K = 64, C = 128, CG = 32, RPT = 4, RT = 32, XS = K + 4;
    __shared__ float Ws[K * C];
    __shared__ float Xs[RT * XS];
    const int t = threadIdx.x;

    for (int i = t * 4; i < K * C; i += 1024)
        *(float4*)&Ws[i] = *(const float4*)&W2[i];

    const int row0 = blockIdx.x * RT;
    for (int i = t * 4; i < RT * K; i += 1024) {
        int r = i / K, k = i % K;
        int gr = row0 + r;
        float4 v = make_float4(0.f, 0.f, 0.f, 0.f);
        if (gr < n) v = *(const float4*)&G[(long long)gr * K + k];
        *(float4*)&Xs[r * XS + k] = v;
    }
    __syncthreads();

    const int cg = t % CG, rs = t / CG;
    float acc[RPT][4];
#pragma unroll
    for (int i = 0; i < RPT; ++i)
#pragma unroll
        for (int j = 0; j < 4; ++j) acc[i][j] = 0.f;

#pragma unroll 4
    for (int k = 0; k < K; ++k) {
        float4 w = *(float4*)&Ws[k * C + cg * 4];
#pragma unroll
        for (int i = 0; i < RPT; ++i) {
            float xv = Xs[(rs * RPT + i) * XS + k];
            acc[i][0] = fmaf(xv, w.x, acc[i][0]);
            acc[i][1] = fmaf(xv, w.y, acc[i][1]);
            acc[i][2] = fmaf(xv, w.z, acc[i][2]);
            acc[i][3] = fmaf(xv, w.w, acc[i][3]);
        }
    }

    float4 bv = *(const float4*)&b2[cg * 4];
    float4 wf = *(const float4*)&Wfc[cg * 4];
#pragma unroll
    for (int i = 0; i < RPT; ++i) {
        float p = fmaxf(acc[i][0] + bv.x, 0.f) * wf.x
                + fmaxf(acc[i][1] + bv.y, 0.f) * wf.y
                + fmaxf(acc[i][2] + bv.z, 0.f) * wf.z
                + fmaxf(acc[i][3] + bv.w, 0.f) * wf.w;
#pragma unroll
        for (int off = 16; off; off >>= 1) p += __shfl_down(p, off, 32);
        int gr = row0 + rs * RPT + i;
        if (cg == 0 && gr < n) out[gr] = p + bfc[0];
    }
}

extern "C" void kernel_launch(void* const* d_in, const int* in_sizes, int n_in,
                              void* d_out, int out_size, void* d_ws, size_t ws_size,
                              hipStream_t stream) {
    const float* x   = (const float*)d_in[0];
    const void*  ei  = d_in[1];
    const float* W1  = (const float*)d_in[2];
    const float* b1  = (const float*)d_in[3];
    const float* W2  = (const float*)d_in[4];
    const float* b2  = (const float*)d_in[5];
    const float* Wfc = (const float*)d_in[6];
    const float* bfc = (const float*)d_in[7];
    float* out = (float*)d_out;

    const int N = NN;
    const int E = in_sizes[1] / 2;

    char* ws = (char*)d_ws;
    size_t o = 0;
    auto carve = [&](size_t bytes) {
        char* p = ws + o;
        o = (o + bytes + 255) & ~(size_t)255;
        return p;
    };
    float*  dinv      = (float*)carve((size_t)N * 4);
    int*    row_ptr   = (int*)carve((size_t)(N + 1) * 4);
    int*    g_bincnt  = (int*)carve((size_t)NBIN * 4);
    int*    g_binstart= (int*)carve((size_t)NBIN * 4);
    int*    flag      = (int*)carve(4);
    int*    csr       = (int*)carve((size_t)E * 4);
    uint2*  binbuf    = (uint2*)carve((size_t)NBIN * CAP * 8);
    __half* bufA      = (__half*)carve((size_t)N * 64 * 2);   // h1s (fp16)
    __half* bufB      = (__half*)carve((size_t)N * 64 * 2);   // h1rs (fp16)
    float*  bufG      = (float*)carve((size_t)N * 64 * 4);    // g2 (fp32)

    const int* ei_lo = (const int*)ei;

    // ---- CSR build via two-pass counting sort ----
    hipMemsetAsync(g_bincnt, 0, (size_t)NBIN * 4, stream);
    k_detect<<<1, 64, 0, stream>>>((const unsigned int*)ei, flag);
    k_binA<<<(E + 4095) / 4096, 256, 0, stream>>>(ei_lo, flag, E, g_bincnt, binbuf);
    k_scanbin<<<1, 64, 0, stream>>>(g_bincnt, g_binstart, row_ptr, N, E);
    k_build<<<NBIN, 512, 0, stream>>>(binbuf, g_bincnt, g_binstart, row_ptr, dinv, csr, N);

    // ---- layer 1: h1s = (x @ W1) * dinv[row]  -> bufA (fp16) ----
    k_gemm1<<<(N + 31) / 32, 256, 0, stream>>>(x, W1, dinv, bufA, N);
    // h1rs = relu(d*(sum + self) + b1) * d  -> bufB (fp16)
    k_gather<true><<<(N + 3) / 4, 256, 0, stream>>>(bufA, row_ptr, csr, dinv, b1, bufB, N);

    // ---- layer 2: g2 = d*(sum + self) of h1rs  -> bufG (fp32) ----
    k_gather<false><<<(N + 3) / 4, 256, 0, stream>>>(bufB, row_ptr, csr, dinv, nullptr, bufG, N);
    // out = relu(g2 @ W2 + b2) . Wfc + bfc
    k_gemm2fc<<<(N + 31) / 32, 256, 0, stream>>>(bufG, W2, b2, Wfc, bfc, out, N);
}

// Round 7
// 301.703 us; speedup vs baseline: 7.5657x; 1.2104x over previous
//
#include <hip/hip_runtime.h>
#include <hip/hip_fp16.h>

#define NN 100000
#define NBIN 128
#define RANGE 782            // ceil(100000/128); 128*782 = 100096 >= 100000
#define CAP 32768            // per-bin capacity (expected ~25e3, sigma ~160)

// ---- detect whether edge_index is int64 (hi words all zero) or int32 ----
__global__ __launch_bounds__(64) void k_detect(const unsigned int* ei, int* flag) {
    if (threadIdx.x == 0) {
        int is64 = 1;
        for (int i = 0; i < 64; ++i)
            if (ei[2 * i + 1] != 0u) { is64 = 0; break; }
        *flag = is64;
    }
}

// ---- pass A: block-level radix scatter of edges into 128 dst-bins ----
// entries packed to u32: (dst - bin*RANGE) << 17 | src   (src < 2^17, dstlo < 2^10)
__global__ __launch_bounds__(256) void k_binA(const int* __restrict__ ei_lo,
                                              const int* __restrict__ flag,
                                              int E, int* __restrict__ g_bincnt,
                                              unsigned* __restrict__ binbuf) {
    constexpr int ITER = 16;
    __shared__ int cnt[NBIN], basep[NBIN], pos[NBIN];
    const int t = threadIdx.x;
    const int base = blockIdx.x * (256 * ITER);
    const int s = (*flag) ? 2 : 1;
    unsigned pk[ITER];
    int bn[ITER];

    for (int i = t; i < NBIN; i += 256) { cnt[i] = 0; pos[i] = 0; }
    __syncthreads();

#pragma unroll
    for (int i = 0; i < ITER; ++i) {
        int e = base + i * 256 + t;
        if (e < E) {
            int src = __builtin_nontemporal_load(&ei_lo[(long long)s * e]);
            int dst = __builtin_nontemporal_load(&ei_lo[(long long)s * (E + e)]);
            int b = dst / RANGE;
            bn[i] = b;
            pk[i] = ((unsigned)(dst - b * RANGE) << 17) | (unsigned)src;
            atomicAdd(&cnt[b], 1);
        } else bn[i] = -1;
    }
    __syncthreads();
    for (int i = t; i < NBIN; i += 256)
        basep[i] = atomicAdd(&g_bincnt[i], cnt[i]);
    __syncthreads();
#pragma unroll
    for (int i = 0; i < ITER; ++i) {
        if (bn[i] >= 0) {
            int r = atomicAdd(&pos[bn[i]], 1);
            binbuf[(long long)bn[i] * CAP + basep[bn[i]] + r] = pk[i];
        }
    }
}

// ---- tiny scan of the 128 bin counts -> bin starts; also row_ptr[N]=E ----
__global__ __launch_bounds__(64) void k_scanbin(const int* __restrict__ g_bincnt,
                                                int* __restrict__ g_binstart,
                                                int* __restrict__ row_ptr, int n, int E) {
    if (threadIdx.x == 0) {
        int run = 0;
        for (int b = 0; b < NBIN; ++b) { g_binstart[b] = run; run += g_bincnt[b]; }
        row_ptr[n] = E;
    }
}

// ---- pass B: one block per bin. LDS histogram -> row_ptr/dinv,
//      then LDS-cursor scatter into csr (no global atomics). ----
__global__ __launch_bounds__(512) void k_build(const unsigned* __restrict__ binbuf,
                                               const int* __restrict__ g_bincnt,
                                               const int* __restrict__ g_binstart,
                                               int* __restrict__ row_ptr,
                                               float* __restrict__ dinv,
                                               int* __restrict__ csr, int n) {
    __shared__ int cnt[1024];
    __shared__ int ssum[512];
    const int t = threadIdx.x;
    const int bin = blockIdx.x;
    const int lo = bin * RANGE;
    const int rn = min(RANGE, n - lo);
    const int nE = g_bincnt[bin];
    const int bstart = g_binstart[bin];
    const unsigned* __restrict__ src = binbuf + (long long)bin * CAP;

    cnt[t] = 0; cnt[t + 512] = 0;
    __syncthreads();
    for (int i = t; i < nE; i += 512)
        atomicAdd(&cnt[(int)(src[i] >> 17)], 1);
    __syncthreads();
    int a = cnt[2 * t], b = cnt[2 * t + 1];
    ssum[t] = a + b;
    __syncthreads();
    for (int off = 1; off < 512; off <<= 1) {
        int add = (t >= off) ? ssum[t - off] : 0;
        __syncthreads();
        ssum[t] += add;
        __syncthreads();
    }
    int prev = (t > 0) ? ssum[t - 1] : 0;  // exclusive over pairs
    cnt[2 * t] = prev;                      // cursor (relative slot)
    cnt[2 * t + 1] = prev + a;
    if (2 * t < rn) {
        row_ptr[lo + 2 * t] = bstart + prev;
        dinv[lo + 2 * t] = rsqrtf((float)a + 1.f);
    }
    if (2 * t + 1 < rn) {
        row_ptr[lo + 2 * t + 1] = bstart + prev + a;
        dinv[lo + 2 * t + 1] = rsqrtf((float)b + 1.f);
    }
    __syncthreads();
    for (int i = t; i < nE; i += 512) {
        unsigned e = src[i];
        int slot = bstart + atomicAdd(&cnt[(int)(e >> 17)], 1);
        csr[slot] = (int)(e & 0x1FFFFu);
    }
}

// ---- GEMM1: H[N,64] = (X[N,128] @ W[128,64]) * dinv[row], fp16 out ----
__global__ __launch_bounds__(256) void k_gemm1(const float* __restrict__ X,
                                               const float* __restrict__ W,
                                               const float* __restrict__ dinv,
                                               __half* __restrict__ H, int n) {
    constexpr int K = 128, C = 64, RPT = 2;
    constexpr int CG = C / 4, RS = 256 / CG, RT = RS * RPT, XS = K + 4;
    __shared__ float Ws[K * C];
    __shared__ float Xs[RT * XS];
    const int t = threadIdx.x;

    for (int i = t * 4; i < K * C; i += 1024)
        *(float4*)&Ws[i] = *(const float4*)&W[i];

    const int row0 = blockIdx.x * RT;
    for (int i = t * 4; i < RT * K; i += 1024) {
        int r = i / K, k = i % K;
        int gr = row0 + r;
        float4 v = make_float4(0.f, 0.f, 0.f, 0.f);
        if (gr < n) v = *(const float4*)&X[(long long)gr * K + k];
        *(float4*)&Xs[r * XS + k] = v;
    }
    __syncthreads();

    const int cg = t % CG, rs = t / CG;
    float acc[RPT][4];
#pragma unroll
    for (int i = 0; i < RPT; ++i)
#pragma unroll
        for (int j = 0; j < 4; ++j) acc[i][j] = 0.f;

#pragma unroll 4
    for (int k = 0; k < K; ++k) {
        float4 w = *(float4*)&Ws[k * C + cg * 4];
#pragma unroll
        for (int i = 0; i < RPT; ++i) {
            float xv = Xs[(rs * RPT + i) * XS + k];
            acc[i][0] = fmaf(xv, w.x, acc[i][0]);
            acc[i][1] = fmaf(xv, w.y, acc[i][1]);
            acc[i][2] = fmaf(xv, w.z, acc[i][2]);
            acc[i][3] = fmaf(xv, w.w, acc[i][3]);
        }
    }
#pragma unroll
    for (int i = 0; i < RPT; ++i) {
        int gr = row0 + rs * RPT + i;
        if (gr < n) {
            float sc = dinv[gr];
            union { __half h[4]; uint2 u; } pk;
            pk.h[0] = __float2half(acc[i][0] * sc);
            pk.h[1] = __float2half(acc[i][1] * sc);
            pk.h[2] = __float2half(acc[i][2] * sc);
            pk.h[3] = __float2half(acc[i][3] * sc);
            *(uint2*)&H[(long long)gr * C + cg * 4] = pk.u;
        }
    }
}

// ---- gather (F=64, fp16 rows, fp32 accum): wave per node, 2 edges/instr ----
// lanes 0-31: even edges, lanes 32-63: odd edges; each lane covers 2 features.
template <bool RELU>
__global__ __launch_bounds__(256) void k_gather(const __half* __restrict__ h,
                                                const int* __restrict__ row_ptr,
                                                const int* __restrict__ csr,
                                                const float* __restrict__ dinv,
                                                const float* __restrict__ bias,
                                                void* __restrict__ outv, int n) {
    int node = blockIdx.x * 4 + (threadIdx.x >> 6);
    int lane = threadIdx.x & 63;
    if (node >= n) return;
    const int half = lane >> 5;
    const int fl = lane & 31;
    float d = dinv[node];
    int beg = row_ptr[node], end = row_ptr[node + 1];
    float ax0 = 0.f, ay0 = 0.f, ax1 = 0.f, ay1 = 0.f;
    float ax2 = 0.f, ay2 = 0.f, ax3 = 0.f, ay3 = 0.f;
    int i = beg;
    for (; i + 7 < end; i += 8) {
        int s0 = csr[i + half];
        int s1 = csr[i + 2 + half];
        int s2 = csr[i + 4 + half];
        int s3 = csr[i + 6 + half];
        float2 f0 = __half22float2(*(const __half2*)&h[(long long)s0 * 64 + fl * 2]);
        float2 f1 = __half22float2(*(const __half2*)&h[(long long)s1 * 64 + fl * 2]);
        float2 f2 = __half22float2(*(const __half2*)&h[(long long)s2 * 64 + fl * 2]);
        float2 f3 = __half22float2(*(const __half2*)&h[(long long)s3 * 64 + fl * 2]);
        ax0 += f0.x; ay0 += f0.y;
        ax1 += f1.x; ay1 += f1.y;
        ax2 += f2.x; ay2 += f2.y;
        ax3 += f3.x; ay3 += f3.y;
    }
    for (; i + 1 < end; i += 2) {
        int s0 = csr[i + half];
        float2 f0 = __half22float2(*(const __half2*)&h[(long long)s0 * 64 + fl * 2]);
        ax0 += f0.x; ay0 += f0.y;
    }
    if (i < end && half == 0) {
        int s0 = csr[i];
        float2 f0 = __half22float2(*(const __half2*)&h[(long long)s0 * 64 + fl * 2]);
        ax0 += f0.x; ay0 += f0.y;
    }
    float accx = (ax0 + ax1) + (ax2 + ax3);
    float accy = (ay0 + ay1) + (ay2 + ay3);
    accx += __shfl_xor(accx, 32, 64);
    accy += __shfl_xor(accy, 32, 64);
    float2 self = __half22float2(*(const __half2*)&h[(long long)node * 64 + fl * 2]);
    accx += self.x;
    accy += self.y;
    if (half == 0) {
        if (RELU) {
            float2 bv = *(const float2*)&bias[fl * 2];
            float vx = fmaxf(fmaf(d, accx, bv.x), 0.f) * d;
            float vy = fmaxf(fmaf(d, accy, bv.y), 0.f) * d;
            union { __half h2[2]; unsigned u; } o;
            o.h2[0] = __float2half(vx);
            o.h2[1] = __float2half(vy);
            *(unsigned*)&((__half*)outv)[(long long)node * 64 + fl * 2] = o.u;
        } else {
            *(float2*)&((float*)outv)[(long long)node * 64 + fl * 2] =
                make_float2(d * accx, d * accy);
        }
    }
}

// ---- fused: out[row] = relu(G[row]@W2 + b2) . Wfc + bfc ----
__global__ __launch_bounds__(256) void k_gemm2fc(const float* __restrict__ G,
                                                 const float* __restrict__ W2,
                                                 const float* __restrict__ b2,
                                                 const float* __restrict__ Wfc,
                                                 const float* __restrict__ bfc,
                                                 float* __restrict__ out, int n) {
    constexpr int K = 64, C = 128, CG = 32, RPT = 4, RT = 32, XS = K + 4;
    __shared__ float Ws[K * C];
    __shared__ float Xs[RT * XS];
    const int t = threadIdx.x;

    for (int i = t * 4; i < K * C; i += 1024)
        *(float4*)&Ws[i] = *(const float4*)&W2[i];

    const int row0 = blockIdx.x * RT;
    for (int i = t * 4; i < RT * K; i += 1024) {
        int r = i / K, k = i % K;
        int gr = row0 + r;
        float4 v = make_float4(0.f, 0.f, 0.f, 0.f);
        if (gr < n) v = *(const float4*)&G[(long long)gr * K + k];
        *(float4*)&Xs[r * XS + k] = v;
    }
    __syncthreads();

    const int cg = t % CG, rs = t / CG;
    float acc[RPT][4];
#pragma unroll
    for (int i = 0; i < RPT; ++i)
#pragma unroll
        for (int j = 0; j < 4; ++j) acc[i][j] = 0.f;

#pragma unroll 4
    for (int k = 0; k < K; ++k) {
        float4 w = *(float4*)&Ws[k * C + cg * 4];
#pragma unroll
        for (int i = 0; i < RPT; ++i) {
            float xv = Xs[(rs * RPT + i) * XS + k];
            acc[i][0] = fmaf(xv, w.x, acc[i][0]);
            acc[i][1] = fmaf(xv, w.y, acc[i][1]);
            acc[i][2] = fmaf(xv, w.z, acc[i][2]);
            acc[i][3] = fmaf(xv, w.w, acc[i][3]);
        }
    }

    float4 bv = *(const float4*)&b2[cg * 4];
    float4 wf = *(const float4*)&Wfc[cg * 4];
#pragma unroll
    for (int i = 0; i < RPT; ++i) {
        float p = fmaxf(acc[i][0] + bv.x, 0.f) * wf.x
                + fmaxf(acc[i][1] + bv.y, 0.f) * wf.y
                + fmaxf(acc[i][2] + bv.z, 0.f) * wf.z
                + fmaxf(acc[i][3] + bv.w, 0.f) * wf.w;
#pragma unroll
        for (int off = 16; off; off >>= 1) p += __shfl_down(p, off, 32);
        int gr = row0 + rs * RPT + i;
        if (cg == 0 && gr < n) out[gr] = p + bfc[0];
    }
}

extern "C" void kernel_launch(void* const* d_in, const int* in_sizes, int n_in,
                              void* d_out, int out_size, void* d_ws, size_t ws_size,
                              hipStream_t stream) {
    const float* x   = (const float*)d_in[0];
    const void*  ei  = d_in[1];
    const float* W1  = (const float*)d_in[2];
    const float* b1  = (const float*)d_in[3];
    const float* W2  = (const float*)d_in[4];
    const float* b2  = (const float*)d_in[5];
    const float* Wfc = (const float*)d_in[6];
    const float* bfc = (const float*)d_in[7];
    float* out = (float*)d_out;

    const int N = NN;
    const int E = in_sizes[1] / 2;

    char* ws = (char*)d_ws;
    size_t o = 0;
    auto carve = [&](size_t bytes) {
        char* p = ws + o;
        o = (o + bytes + 255) & ~(size_t)255;
        return p;
    };
    float*    dinv      = (float*)carve((size_t)N * 4);
    int*      row_ptr   = (int*)carve((size_t)(N + 1) * 4);
    int*      g_bincnt  = (int*)carve((size_t)NBIN * 4);
    int*      g_binstart= (int*)carve((size_t)NBIN * 4);
    int*      flag      = (int*)carve(4);
    int*      csr       = (int*)carve((size_t)E * 4);
    unsigned* binbuf    = (unsigned*)carve((size_t)NBIN * CAP * 4);
    __half*   bufA      = (__half*)carve((size_t)N * 64 * 2);   // h1s (fp16)
    __half*   bufB      = (__half*)carve((size_t)N * 64 * 2);   // h1rs (fp16)
    float*    bufG      = (float*)carve((size_t)N * 64 * 4);    // g2 (fp32)

    const int* ei_lo = (const int*)ei;

    // ---- CSR build via two-pass counting sort ----
    hipMemsetAsync(g_bincnt, 0, (size_t)NBIN * 4, stream);
    k_detect<<<1, 64, 0, stream>>>((const unsigned int*)ei, flag);
    k_binA<<<(E + 4095) / 4096, 256, 0, stream>>>(ei_lo, flag, E, g_bincnt, binbuf);
    k_scanbin<<<1, 64, 0, stream>>>(g_bincnt, g_binstart, row_ptr, N, E);
    k_build<<<NBIN, 512, 0, stream>>>(binbuf, g_bincnt, g_binstart, row_ptr, dinv, csr, N);

    // ---- layer 1: h1s = (x @ W1) * dinv[row]  -> bufA (fp16) ----
    k_gemm1<<<(N + 31) / 32, 256, 0, stream>>>(x, W1, dinv, bufA, N);
    // h1rs = relu(d*(sum + self) + b1) * d  -> bufB (fp16)
    k_gather<true><<<(N + 3) / 4, 256, 0, stream>>>(bufA, row_ptr, csr, dinv, b1, bufB, N);

    // ---- layer 2: g2 = d*(sum + self) of h1rs  -> bufG (fp32) ----
    k_gather<false><<<(N + 3) / 4, 256, 0, stream>>>(bufB, row_ptr, csr, dinv, nullptr, bufG, N);
    // out = relu(g2 @ W2 + b2) . Wfc + bfc
    k_gemm2fc<<<(N + 31) / 32, 256, 0, stream>>>(bufG, W2, b2, Wfc, bfc, out, N);
}

// Round 8
// 287.408 us; speedup vs baseline: 7.9420x; 1.0497x over previous
//
#include <hip/hip_runtime.h>
#include <hip/hip_fp16.h>

#define NN 100000
#define NBIN 128
#define RANGE 782            // ceil(100000/128); 128*782 = 100096 >= 100000
#define CAP 32768            // per-bin capacity (expected ~25e3, sigma ~160)

// ---- detect whether edge_index is int64 (hi words all zero) or int32 ----
__global__ __launch_bounds__(64) void k_detect(const unsigned int* ei, int* flag) {
    if (threadIdx.x == 0) {
        int is64 = 1;
        for (int i = 0; i < 64; ++i)
            if (ei[2 * i + 1] != 0u) { is64 = 0; break; }
        *flag = is64;
    }
}

// ---- pass A: block-level radix scatter of edges into 128 dst-bins ----
// entries packed to u32: (dst - bin*RANGE) << 17 | src   (src < 2^17, dstlo < 2^10)
__global__ __launch_bounds__(256) void k_binA(const int* __restrict__ ei_lo,
                                              const int* __restrict__ flag,
                                              int E, int* __restrict__ g_bincnt,
                                              unsigned* __restrict__ binbuf) {
    constexpr int ITER = 16;
    __shared__ int cnt[NBIN], basep[NBIN], pos[NBIN];
    const int t = threadIdx.x;
    const int base = blockIdx.x * (256 * ITER);
    const int s = (*flag) ? 2 : 1;
    unsigned pk[ITER];
    int bn[ITER];

    for (int i = t; i < NBIN; i += 256) { cnt[i] = 0; pos[i] = 0; }
    __syncthreads();

#pragma unroll
    for (int i = 0; i < ITER; ++i) {
        int e = base + i * 256 + t;
        if (e < E) {
            int src = __builtin_nontemporal_load(&ei_lo[(long long)s * e]);
            int dst = __builtin_nontemporal_load(&ei_lo[(long long)s * (E + e)]);
            int b = dst / RANGE;
            bn[i] = b;
            pk[i] = ((unsigned)(dst - b * RANGE) << 17) | (unsigned)src;
            atomicAdd(&cnt[b], 1);
        } else bn[i] = -1;
    }
    __syncthreads();
    for (int i = t; i < NBIN; i += 256)
        basep[i] = atomicAdd(&g_bincnt[i], cnt[i]);
    __syncthreads();
#pragma unroll
    for (int i = 0; i < ITER; ++i) {
        if (bn[i] >= 0) {
            int r = atomicAdd(&pos[bn[i]], 1);
            binbuf[(long long)bn[i] * CAP + basep[bn[i]] + r] = pk[i];
        }
    }
}

// ---- tiny scan of the 128 bin counts -> bin starts; also row_ptr[N]=E ----
__global__ __launch_bounds__(64) void k_scanbin(const int* __restrict__ g_bincnt,
                                                int* __restrict__ g_binstart,
                                                int* __restrict__ row_ptr, int n, int E) {
    if (threadIdx.x == 0) {
        int run = 0;
        for (int b = 0; b < NBIN; ++b) { g_binstart[b] = run; run += g_bincnt[b]; }
        row_ptr[n] = E;
    }
}

// ---- pass B: one block per bin. LDS histogram -> row_ptr/dinv,
//      then LDS-cursor scatter into csr (no global atomics). ----
__global__ __launch_bounds__(512) void k_build(const unsigned* __restrict__ binbuf,
                                               const int* __restrict__ g_bincnt,
                                               const int* __restrict__ g_binstart,
                                               int* __restrict__ row_ptr,
                                               float* __restrict__ dinv,
                                               int* __restrict__ csr, int n) {
    __shared__ int cnt[1024];
    __shared__ int ssum[512];
    const int t = threadIdx.x;
    const int bin = blockIdx.x;
    const int lo = bin * RANGE;
    const int rn = min(RANGE, n - lo);
    const int nE = g_bincnt[bin];
    const int bstart = g_binstart[bin];
    const unsigned* __restrict__ src = binbuf + (long long)bin * CAP;

    cnt[t] = 0; cnt[t + 512] = 0;
    __syncthreads();
    for (int i = t; i < nE; i += 512)
        atomicAdd(&cnt[(int)(src[i] >> 17)], 1);
    __syncthreads();
    int a = cnt[2 * t], b = cnt[2 * t + 1];
    ssum[t] = a + b;
    __syncthreads();
    for (int off = 1; off < 512; off <<= 1) {
        int add = (t >= off) ? ssum[t - off] : 0;
        __syncthreads();
        ssum[t] += add;
        __syncthreads();
    }
    int prev = (t > 0) ? ssum[t - 1] : 0;  // exclusive over pairs
    cnt[2 * t] = prev;                      // cursor (relative slot)
    cnt[2 * t + 1] = prev + a;
    if (2 * t < rn) {
        row_ptr[lo + 2 * t] = bstart + prev;
        dinv[lo + 2 * t] = rsqrtf((float)a + 1.f);
    }
    if (2 * t + 1 < rn) {
        row_ptr[lo + 2 * t + 1] = bstart + prev + a;
        dinv[lo + 2 * t + 1] = rsqrtf((float)b + 1.f);
    }
    __syncthreads();
    for (int i = t; i < nE; i += 512) {
        unsigned e = src[i];
        int slot = bstart + atomicAdd(&cnt[(int)(e >> 17)], 1);
        csr[slot] = (int)(e & 0x1FFFFu);
    }
}

// ---- GEMM1: H[N,64] = (X[N,128] @ W[128,64]) * dinv[row], fp16 out ----
__global__ __launch_bounds__(256) void k_gemm1(const float* __restrict__ X,
                                               const float* __restrict__ W,
                                               const float* __restrict__ dinv,
                                               __half* __restrict__ H, int n) {
    constexpr int K = 128, C = 64, RPT = 2;
    constexpr int CG = C / 4, RS = 256 / CG, RT = RS * RPT, XS = K + 4;
    __shared__ float Ws[K * C];
    __shared__ float Xs[RT * XS];
    const int t = threadIdx.x;

    for (int i = t * 4; i < K * C; i += 1024)
        *(float4*)&Ws[i] = *(const float4*)&W[i];

    const int row0 = blockIdx.x * RT;
    for (int i = t * 4; i < RT * K; i += 1024) {
        int r = i / K, k = i % K;
        int gr = row0 + r;
        float4 v = make_float4(0.f, 0.f, 0.f, 0.f);
        if (gr < n) v = *(const float4*)&X[(long long)gr * K + k];
        *(float4*)&Xs[r * XS + k] = v;
    }
    __syncthreads();

    const int cg = t % CG, rs = t / CG;
    float acc[RPT][4];
#pragma unroll
    for (int i = 0; i < RPT; ++i)
#pragma unroll
        for (int j = 0; j < 4; ++j) acc[i][j] = 0.f;

#pragma unroll 2
    for (int k4 = 0; k4 < K / 4; ++k4) {
        float4 xv[RPT];
#pragma unroll
        for (int i = 0; i < RPT; ++i)
            xv[i] = *(float4*)&Xs[(rs * RPT + i) * XS + k4 * 4];
#pragma unroll
        for (int j = 0; j < 4; ++j) {
            float4 w = *(float4*)&Ws[(k4 * 4 + j) * C + cg * 4];
#pragma unroll
            for (int i = 0; i < RPT; ++i) {
                float xvj = (&xv[i].x)[j];
                acc[i][0] = fmaf(xvj, w.x, acc[i][0]);
                acc[i][1] = fmaf(xvj, w.y, acc[i][1]);
                acc[i][2] = fmaf(xvj, w.z, acc[i][2]);
                acc[i][3] = fmaf(xvj, w.w, acc[i][3]);
            }
        }
    }
#pragma unroll
    for (int i = 0; i < RPT; ++i) {
        int gr = row0 + rs * RPT + i;
        if (gr < n) {
            float sc = dinv[gr];
            union { __half h[4]; uint2 u; } pk;
            pk.h[0] = __float2half(acc[i][0] * sc);
            pk.h[1] = __float2half(acc[i][1] * sc);
            pk.h[2] = __float2half(acc[i][2] * sc);
            pk.h[3] = __float2half(acc[i][3] * sc);
            *(uint2*)&H[(long long)gr * C + cg * 4] = pk.u;
        }
    }
}

// ---- gather (F=64, fp16 rows, fp32 accum): wave per node, 8 lanes/edge ----
// group g = lane>>3 owns edge i+g; lane covers features 8*(lane&7)..+7 (dwordx4).
template <bool RELU>
__global__ __launch_bounds__(256) void k_gather(const __half* __restrict__ h,
                                                const int* __restrict__ row_ptr,
                                                const int* __restrict__ csr,
                                                const float* __restrict__ dinv,
                                                const float* __restrict__ bias,
                                                void* __restrict__ outv, int n) {
    int node = blockIdx.x * 4 + (threadIdx.x >> 6);
    int lane = threadIdx.x & 63;
    if (node >= n) return;
    const int g = lane >> 3;
    const int fl = lane & 7;
    float d = dinv[node];
    int beg = row_ptr[node], end = row_ptr[node + 1];
    float a0 = 0.f, a1 = 0.f, a2 = 0.f, a3 = 0.f;
    float a4 = 0.f, a5 = 0.f, a6 = 0.f, a7 = 0.f;
    float b0 = 0.f, b1 = 0.f, b2 = 0.f, b3 = 0.f;
    float b4 = 0.f, b5 = 0.f, b6 = 0.f, b7 = 0.f;
    for (int i = beg; i < end; i += 16) {
        int e0 = i + g, e1 = i + 8 + g;
        if (e0 < end) {
            int s = csr[e0];
            uint4 u = *(const uint4*)&h[(long long)s * 64 + fl * 8];
            float2 f0 = __half22float2(*(__half2*)&u.x);
            float2 f1 = __half22float2(*(__half2*)&u.y);
            float2 f2 = __half22float2(*(__half2*)&u.z);
            float2 f3 = __half22float2(*(__half2*)&u.w);
            a0 += f0.x; a1 += f0.y; a2 += f1.x; a3 += f1.y;
            a4 += f2.x; a5 += f2.y; a6 += f3.x; a7 += f3.y;
        }
        if (e1 < end) {
            int s = csr[e1];
            uint4 u = *(const uint4*)&h[(long long)s * 64 + fl * 8];
            float2 f0 = __half22float2(*(__half2*)&u.x);
            float2 f1 = __half22float2(*(__half2*)&u.y);
            float2 f2 = __half22float2(*(__half2*)&u.z);
            float2 f3 = __half22float2(*(__half2*)&u.w);
            b0 += f0.x; b1 += f0.y; b2 += f1.x; b3 += f1.y;
            b4 += f2.x; b5 += f2.y; b6 += f3.x; b7 += f3.y;
        }
    }
    float r0 = a0 + b0, r1 = a1 + b1, r2 = a2 + b2, r3 = a3 + b3;
    float r4 = a4 + b4, r5 = a5 + b5, r6 = a6 + b6, r7 = a7 + b7;
#pragma unroll
    for (int off = 8; off <= 32; off <<= 1) {
        r0 += __shfl_xor(r0, off, 64);
        r1 += __shfl_xor(r1, off, 64);
        r2 += __shfl_xor(r2, off, 64);
        r3 += __shfl_xor(r3, off, 64);
        r4 += __shfl_xor(r4, off, 64);
        r5 += __shfl_xor(r5, off, 64);
        r6 += __shfl_xor(r6, off, 64);
        r7 += __shfl_xor(r7, off, 64);
    }
    if (g == 0) {
        uint4 su = *(const uint4*)&h[(long long)node * 64 + fl * 8];
        float2 s0 = __half22float2(*(__half2*)&su.x);
        float2 s1 = __half22float2(*(__half2*)&su.y);
        float2 s2 = __half22float2(*(__half2*)&su.z);
        float2 s3 = __half22float2(*(__half2*)&su.w);
        r0 += s0.x; r1 += s0.y; r2 += s1.x; r3 += s1.y;
        r4 += s2.x; r5 += s2.y; r6 += s3.x; r7 += s3.y;
        if (RELU) {
            float4 bv0 = *(const float4*)&bias[fl * 8];
            float4 bv1 = *(const float4*)&bias[fl * 8 + 4];
            union { __half hh[8]; uint4 u; } o;
            o.hh[0] = __float2half(fmaxf(fmaf(d, r0, bv0.x), 0.f) * d);
            o.hh[1] = __float2half(fmaxf(fmaf(d, r1, bv0.y), 0.f) * d);
            o.hh[2] = __float2half(fmaxf(fmaf(d, r2, bv0.z), 0.f) * d);
            o.hh[3] = __float2half(fmaxf(fmaf(d, r3, bv0.w), 0.f) * d);
            o.hh[4] = __float2half(fmaxf(fmaf(d, r4, bv1.x), 0.f) * d);
            o.hh[5] = __float2half(fmaxf(fmaf(d, r5, bv1.y), 0.f) * d);
            o.hh[6] = __float2half(fmaxf(fmaf(d, r6, bv1.z), 0.f) * d);
            o.hh[7] = __float2half(fmaxf(fmaf(d, r7, bv1.w), 0.f) * d);
            *(uint4*)&((__half*)outv)[(long long)node * 64 + fl * 8] = o.u;
        } else {
            float* op = (float*)outv + (long long)node * 64 + fl * 8;
            *(float4*)op = make_float4(d * r0, d * r1, d * r2, d * r3);
            *(float4*)(op + 4) = make_float4(d * r4, d * r5, d * r6, d * r7);
        }
    }
}

// ---- fused: out[row] = relu(G[row]@W2 + b2) . Wfc + bfc ----
__global__ __launch_bounds__(256) void k_gemm2fc(const float* __restrict__ G,
                                                 const float* __restrict__ W2,
                                                 const float* __restrict__ b2,
                                                 const float* __restrict__ Wfc,
                                                 const float* __restrict__ bfc,
                                                 float* __restrict__ out, int n) {
    constexpr int K = 64, C = 128, CG = 32, RPT = 4, RT = 32, XS = K + 4;
    __shared__ float Ws[K * C];
    __shared__ float Xs[RT * XS];
    const int t = threadIdx.x;

    for (int i = t * 4; i < K * C; i += 1024)
        *(float4*)&Ws[i] = *(const float4*)&W2[i];

    const int row0 = blockIdx.x * RT;
    for (int i = t * 4; i < RT * K; i += 1024) {
        int r = i / K, k = i % K;
        int gr = row0 + r;
        float4 v = make_float4(0.f, 0.f, 0.f, 0.f);
        if (gr < n) v = *(const float4*)&G[(long long)gr * K + k];
        *(float4*)&Xs[r * XS + k] = v;
    }
    __syncthreads();

    const int cg = t % CG, rs = t / CG;
    float acc[RPT][4];
#pragma unroll
    for (int i = 0; i < RPT; ++i)
#pragma unroll
        for (int j = 0; j < 4; ++j) acc[i][j] = 0.f;

#pragma unroll 2
    for (int k4 = 0; k4 < K / 4; ++k4) {
        float4 xv[RPT];
#pragma unroll
        for (int i = 0; i < RPT; ++i)
            xv[i] = *(float4*)&Xs[(rs * RPT + i) * XS + k4 * 4];
#pragma unroll
        for (int j = 0; j < 4; ++j) {
            float4 w = *(float4*)&Ws[(k4 * 4 + j) * C + cg * 4];
#pragma unroll
            for (int i = 0; i < RPT; ++i) {
                float xvj = (&xv[i].x)[j];
                acc[i][0] = fmaf(xvj, w.x, acc[i][0]);
                acc[i][1] = fmaf(xvj, w.y, acc[i][1]);
                acc[i][2] = fmaf(xvj, w.z, acc[i][2]);
                acc[i][3] = fmaf(xvj, w.w, acc[i][3]);
            }
        }
    }

    float4 bv = *(const float4*)&b2[cg * 4];
    float4 wf = *(const float4*)&Wfc[cg * 4];
#pragma unroll
    for (int i = 0; i < RPT; ++i) {
        float p = fmaxf(acc[i][0] + bv.x, 0.f) * wf.x
                + fmaxf(acc[i][1] + bv.y, 0.f) * wf.y
                + fmaxf(acc[i][2] + bv.z, 0.f) * wf.z
                + fmaxf(acc[i][3] + bv.w, 0.f) * wf.w;
#pragma unroll
        for (int off = 16; off; off >>= 1) p += __shfl_down(p, off, 32);
        int gr = row0 + rs * RPT + i;
        if (cg == 0 && gr < n) out[gr] = p + bfc[0];
    }
}

extern "C" void kernel_launch(void* const* d_in, const int* in_sizes, int n_in,
                              void* d_out, int out_size, void* d_ws, size_t ws_size,
                              hipStream_t stream) {
    const float* x   = (const float*)d_in[0];
    const void*  ei  = d_in[1];
    const float* W1  = (const float*)d_in[2];
    const float* b1  = (const float*)d_in[3];
    const float* W2  = (const float*)d_in[4];
    const float* b2  = (const float*)d_in[5];
    const float* Wfc = (const float*)d_in[6];
    const float* bfc = (const float*)d_in[7];
    float* out = (float*)d_out;

    const int N = NN;
    const int E = in_sizes[1] / 2;

    char* ws = (char*)d_ws;
    size_t o = 0;
    auto carve = [&](size_t bytes) {
        char* p = ws + o;
        o = (o + bytes + 255) & ~(size_t)255;
        return p;
    };
    float*    dinv      = (float*)carve((size_t)N * 4);
    int*      row_ptr   = (int*)carve((size_t)(N + 1) * 4);
    int*      g_bincnt  = (int*)carve((size_t)NBIN * 4);
    int*      g_binstart= (int*)carve((size_t)NBIN * 4);
    int*      flag      = (int*)carve(4);
    int*      csr       = (int*)carve((size_t)E * 4);
    unsigned* binbuf    = (unsigned*)carve((size_t)NBIN * CAP * 4);
    __half*   bufA      = (__half*)carve((size_t)N * 64 * 2);   // h1s (fp16)
    __half*   bufB      = (__half*)carve((size_t)N * 64 * 2);   // h1rs (fp16)
    float*    bufG      = (float*)carve((size_t)N * 64 * 4);    // g2 (fp32)

    const int* ei_lo = (const int*)ei;

    // ---- CSR build via two-pass counting sort ----
    hipMemsetAsync(g_bincnt, 0, (size_t)NBIN * 4, stream);
    k_detect<<<1, 64, 0, stream>>>((const unsigned int*)ei, flag);
    k_binA<<<(E + 4095) / 4096, 256, 0, stream>>>(ei_lo, flag, E, g_bincnt, binbuf);
    k_scanbin<<<1, 64, 0, stream>>>(g_bincnt, g_binstart, row_ptr, N, E);
    k_build<<<NBIN, 512, 0, stream>>>(binbuf, g_bincnt, g_binstart, row_ptr, dinv, csr, N);

    // ---- layer 1: h1s = (x @ W1) * dinv[row]  -> bufA (fp16) ----
    k_gemm1<<<(N + 31) / 32, 256, 0, stream>>>(x, W1, dinv, bufA, N);
    // h1rs = relu(d*(sum + self) + b1) * d  -> bufB (fp16)
    k_gather<true><<<(N + 3) / 4, 256, 0, stream>>>(bufA, row_ptr, csr, dinv, b1, bufB, N);

    // ---- layer 2: g2 = d*(sum + self) of h1rs  -> bufG (fp32) ----
    k_gather<false><<<(N + 3) / 4, 256, 0, stream>>>(bufB, row_ptr, csr, dinv, nullptr, bufG, N);
    // out = relu(g2 @ W2 + b2) . Wfc + bfc
    k_gemm2fc<<<(N + 31) / 32, 256, 0, stream>>>(bufG, W2, b2, Wfc, bfc, out, N);
}